// Round 11
// baseline (356.850 us; speedup 1.0000x reference)
//
#include <hip/hip_runtime.h>
#include <hip/hip_bf16.h>

typedef __bf16 bf16_t;
typedef __attribute__((ext_vector_type(4))) float f32x4;
typedef __attribute__((ext_vector_type(8))) bf16_t bf16x8;
typedef __attribute__((ext_vector_type(4))) bf16_t bf16x4;
typedef __attribute__((ext_vector_type(2))) bf16_t bf16x2;

#define D_MODEL 1536
#define NH 12
#define DHD 128
#define S_TXT 512
#define S_TOT 1536
#define FF_DIM 6144
#define KVSPLIT 4
#define HQB 288   // 12 heads * 24 q-blocks

// async global->LDS, 16 B per lane. LDS dest is wave-uniform base (+lane*16 by HW).
__device__ inline void gload16(const void* g, void* l) {
    __builtin_amdgcn_global_load_lds((const __attribute__((address_space(1))) unsigned int*)g,
                                     (__attribute__((address_space(3))) unsigned int*)l, 16, 0, 0);
}

// ---------------------------------------------------------------------------
// adaLN stage 1: partial dot products, K split 8 ways. grid (72,8) block 256.
// ---------------------------------------------------------------------------
__global__ __launch_bounds__(256)
void adaln_p(const float* __restrict__ temb,
             const float* __restrict__ w_img, const float* __restrict__ w_txt,
             float* __restrict__ part) {
    __shared__ float t[192];
    int tid = threadIdx.x;
    int k0 = blockIdx.y * 192;
    if (tid < 192) {
        float x = temb[k0 + tid];
        t[tid] = x / (1.0f + __expf(-x));
    }
    __syncthreads();
    int n_g = blockIdx.x * 256 + tid;
    bool img = n_g < 9216;
    const float* W = img ? w_img : w_txt;
    int n = img ? n_g : n_g - 9216;
    float acc = 0.f;
    for (int kk = 0; kk < 192; kk += 4) {
        acc += t[kk]     * W[(size_t)(k0 + kk) * 9216 + n];
        acc += t[kk + 1] * W[(size_t)(k0 + kk + 1) * 9216 + n];
        acc += t[kk + 2] * W[(size_t)(k0 + kk + 2) * 9216 + n];
        acc += t[kk + 3] * W[(size_t)(k0 + kk + 3) * 9216 + n];
    }
    part[(size_t)blockIdx.y * 18432 + n_g] = acc;
}

// adaLN stage 2: reduce + bias. grid 72 x 256.
__global__ __launch_bounds__(256)
void adaln_r(const float* __restrict__ part,
             const float* __restrict__ b_img, const float* __restrict__ b_txt,
             float* __restrict__ emb_img, float* __restrict__ emb_txt) {
    int n_g = blockIdx.x * 256 + threadIdx.x;
    float a = 0.f;
#pragma unroll
    for (int kc = 0; kc < 8; ++kc) a += part[(size_t)kc * 18432 + n_g];
    if (n_g < 9216) emb_img[n_g] = a + b_img[n_g];
    else            emb_txt[n_g - 9216] = a + b_txt[n_g - 9216];
}

// ---------------------------------------------------------------------------
// LayerNorm + modulate -> bf16. Rows 0..511 txt, 512..1535 img.
// ---------------------------------------------------------------------------
__global__ __launch_bounds__(256)
void ln_mod(const float* __restrict__ src_txt, const float* __restrict__ src_img,
            const float* __restrict__ emb_t, const float* __restrict__ emb_i,
            int sh_c, int sc_c, bf16_t* __restrict__ out) {
    int row = blockIdx.x;
    bool txt = row < S_TXT;
    const float* src = txt ? src_txt + (size_t)row * D_MODEL
                           : src_img + (size_t)(row - S_TXT) * D_MODEL;
    const float* emb = txt ? emb_t : emb_i;
    int tid = threadIdx.x;
    float2 v[3];
    float s = 0.f, sq = 0.f;
#pragma unroll
    for (int i = 0; i < 3; ++i) {
        v[i] = *(const float2*)(src + tid * 2 + 512 * i);
        s  += v[i].x + v[i].y;
        sq += v[i].x * v[i].x + v[i].y * v[i].y;
    }
#pragma unroll
    for (int off = 32; off > 0; off >>= 1) {
        s  += __shfl_down(s, off);
        sq += __shfl_down(sq, off);
    }
    __shared__ float red[8];
    int wave = tid >> 6, lane = tid & 63;
    if (lane == 0) { red[wave] = s; red[4 + wave] = sq; }
    __syncthreads();
    float ts = red[0] + red[1] + red[2] + red[3];
    float tq = red[4] + red[5] + red[6] + red[7];
    float mean = ts * (1.0f / D_MODEL);
    float var  = tq * (1.0f / D_MODEL) - mean * mean;
    float rstd = rsqrtf(var + 1e-6f);
    bf16_t* op = out + (size_t)row * D_MODEL;
#pragma unroll
    for (int i = 0; i < 3; ++i) {
        int c0 = tid * 2 + 512 * i;
        bf16x2 r;
        r[0] = (bf16_t)((v[i].x - mean) * rstd * (1.0f + emb[sc_c * D_MODEL + c0])     + emb[sh_c * D_MODEL + c0]);
        r[1] = (bf16_t)((v[i].y - mean) * rstd * (1.0f + emb[sc_c * D_MODEL + c0 + 1]) + emb[sh_c * D_MODEL + c0 + 1]);
        *(bf16x2*)(op + c0) = r;
    }
}

// ---------------------------------------------------------------------------
// Weight convert+transpose: W f32 [K][N] -> Wt bf16 [N][K]. grid (N/64,K/64,2).
// ---------------------------------------------------------------------------
template <int K, int N>
__global__ __launch_bounds__(256)
void conv_wt(const float* __restrict__ w_t, const float* __restrict__ w_i,
             bf16_t* __restrict__ dst) {
    __shared__ float tile[64][65];
    const float* src = blockIdx.z ? w_i : w_t;
    bf16_t* d = dst + (size_t)blockIdx.z * N * K;
    int bn = blockIdx.x * 64, bk = blockIdx.y * 64;
    int tid = threadIdx.x;
#pragma unroll
    for (int j = 0; j < 4; ++j) {
        int k = (tid >> 4) + 16 * j, c4 = tid & 15;
        float4 v = *(const float4*)(src + (size_t)(bk + k) * N + bn + c4 * 4);
        tile[k][c4 * 4 + 0] = v.x;
        tile[k][c4 * 4 + 1] = v.y;
        tile[k][c4 * 4 + 2] = v.z;
        tile[k][c4 * 4 + 3] = v.w;
    }
    __syncthreads();
#pragma unroll
    for (int j = 0; j < 4; ++j) {
        int n = (tid >> 4) + 16 * j, k4 = tid & 15;
        bf16x4 o;
        o[0] = (bf16_t)tile[k4 * 4 + 0][n];
        o[1] = (bf16_t)tile[k4 * 4 + 1][n];
        o[2] = (bf16_t)tile[k4 * 4 + 2][n];
        o[3] = (bf16_t)tile[k4 * 4 + 3][n];
        *(bf16x4*)(d + (size_t)(bn + n) * K + bk + k4 * 4) = o;
    }
}

// ---------------------------------------------------------------------------
// gemmU: unified GEMM, out(MxN) = A(MxK)@Wt(NxK)^T (+ K-split via blockIdx.z).
// 128x64 tile, BK=128, 4 waves, single-buffer 48 KB LDS (3 blk/CU cap),
// m97 2-barrier loop -- BK=128 halves the per-block barrier/drain count.
// L2 supertile swizzle (6-row x CC-col chunk per XCD). 16-chunk XOR swizzle:
// src chunk ((c&7)^(row&7))|(c&8), read (((kc&7)^(rr&7))|(kc&8)).
// EPI: 0=bias(bf16) 1=bias+gelu(bf16) 2=resid+gate(f32) 3=raw partial (bf16,
// z-th partial at out + z*1536*ldo; z==2 goes to out_alt).
// ---------------------------------------------------------------------------
template <int EPI, typename OutT>
__global__ __launch_bounds__(256)
void gemmU(const bf16_t* __restrict__ A, int lda,
           const bf16_t* __restrict__ Wt, int ldw, int wimg_off,
           const float* __restrict__ bias_t, const float* __restrict__ bias_i,
           const float* __restrict__ resid_t, const float* __restrict__ resid_i, int ldr,
           const float* __restrict__ gate_t, const float* __restrict__ gate_i,
           OutT* __restrict__ out, OutT* __restrict__ out_alt, int ldo, int Ks) {
    __shared__ bf16_t As[128 * 128];
    __shared__ bf16_t Bs[64 * 128];
    const int tid = threadIdx.x;

    const int nbx = gridDim.x, nby = gridDim.y;
    const int nwg = nbx * nby;
    const int lb0 = blockIdx.y * nbx + blockIdx.x;
    int bmT, bnT;
    if (nby == 12 && (nbx & 3) == 0 && (nwg & 7) == 0) {
        const int CC = nbx >> 2;
        const int xcd = lb0 & 7, c = lb0 >> 3;
        bmT = (xcd & 1) * 6 + (c % 6);
        bnT = (xcd >> 1) * CC + (c / 6);
    } else {
        int lb = lb0;
        if ((nwg & 7) == 0) lb = (lb & 7) * (nwg >> 3) + (lb >> 3);
        bmT = lb / nbx; bnT = lb % nbx;
    }
    const int bm = bmT * 128, bn = bnT * 64;
    const int koff = blockIdx.z * Ks;

    const bool txt = bm < S_TXT;
    const bf16_t* W = txt ? Wt : Wt + wimg_off;
    const float* bias = txt ? bias_t : bias_i;
    const int wave = tid >> 6, lane = tid & 63;
    const int wr = (wave >> 1) * 64, wc = (wave & 1) * 32;
    const int lr = lane & 15, lg = lane >> 4;

    // staging: 16 rows/round (row = wave*4 + lane>>4 + j*16), 16 chunks of 8.
    const int srow = wave * 4 + (lane >> 4);
    const int c16 = lane & 15;
    const int csrc = ((((c16 & 7) ^ (srow & 7)) | (c16 & 8)) * 8);
    const bf16_t* Ab = A + (size_t)(bm + srow) * lda + koff + csrc;
    const bf16_t* Wb = W + (size_t)(bn + srow) * ldw + koff + csrc;
    const int ldst = srow * 128 - (lane >> 4) * 128;   // wave*4*128 (wave-uniform)

    f32x4 acc[4][2] = {};
    const int nt = Ks >> 7;

    for (int t = 0; t < nt; ++t) {
#pragma unroll
        for (int j = 0; j < 8; ++j)
            gload16(Ab + (size_t)(j * 16) * lda + t * 128, &As[ldst + j * 2048]);
#pragma unroll
        for (int j = 0; j < 4; ++j)
            gload16(Wb + (size_t)(j * 16) * ldw + t * 128, &Bs[ldst + j * 2048]);
        __syncthreads();   // drains vmcnt -> tiles ready
#pragma unroll
        for (int kk = 0; kk < 4; ++kk) {
            const int kc = kk * 4 + lg;
            bf16x8 af[4], bfm[2];
#pragma unroll
            for (int m = 0; m < 4; ++m) {
                int rr = wr + m * 16 + lr;
                af[m] = *(const bf16x8*)&As[rr * 128 + ((((kc & 7) ^ (rr & 7)) | (kc & 8)) * 8)];
            }
#pragma unroll
            for (int n = 0; n < 2; ++n) {
                int rr = wc + n * 16 + lr;
                bfm[n] = *(const bf16x8*)&Bs[rr * 128 + ((((kc & 7) ^ (rr & 7)) | (kc & 8)) * 8)];
            }
#pragma unroll
            for (int m = 0; m < 4; ++m)
#pragma unroll
                for (int n = 0; n < 2; ++n)
                    acc[m][n] = __builtin_amdgcn_mfma_f32_16x16x32_bf16(af[m], bfm[n], acc[m][n], 0, 0, 0);
        }
        __syncthreads();   // reads done before next stage overwrites
    }

    OutT* obase = out;
    if constexpr (EPI == 3)
        obase = (blockIdx.z == 2) ? out_alt : out + (size_t)blockIdx.z * S_TOT * ldo;
    const float* gate  = txt ? gate_t : gate_i;
    const float* resid = txt ? resid_t : resid_i;
    const int rbase = txt ? 0 : S_TXT;
#pragma unroll
    for (int m = 0; m < 4; ++m) {
#pragma unroll
        for (int r = 0; r < 4; ++r) {
            int grow = bm + wr + m * 16 + lg * 4 + r;
#pragma unroll
            for (int n = 0; n < 2; ++n) {
                int gcol = bn + wc + n * 16 + lr;
                float v = acc[m][n][r];
                if constexpr (EPI != 3) v += bias[gcol];
                if constexpr (EPI == 1) {
                    float x = v;
                    float th = tanhf(0.7978845608028654f * (x + 0.044715f * x * x * x));
                    v = 0.5f * x * (1.0f + th);
                } else if constexpr (EPI == 2) {
                    v = resid[(size_t)(grow - rbase) * ldr + gcol] + gate[gcol] * v;
                }
                obase[(size_t)grow * ldo + gcol] = (OutT)v;
            }
        }
    }
}

// ---------------------------------------------------------------------------
// K-split reduce: out = resid + gate*(bias + sum_s partial_s). grid 1536 x 256.
// partials bf16 [NS][1536][1536]; s==2 read from p_alt.
// ---------------------------------------------------------------------------
template <int NS>
__global__ __launch_bounds__(256)
void gemm_red(const bf16_t* __restrict__ p, const bf16_t* __restrict__ p_alt,
              const float* __restrict__ bias_t, const float* __restrict__ bias_i,
              const float* __restrict__ gate_t, const float* __restrict__ gate_i,
              const float* __restrict__ resid_t, const float* __restrict__ resid_i,
              float* __restrict__ out) {
    int r = blockIdx.x;
    bool txt = r < S_TXT;
    const float* bias = txt ? bias_t : bias_i;
    const float* gate = txt ? gate_t : gate_i;
    const float* resid = txt ? resid_t + (size_t)r * D_MODEL
                             : resid_i + (size_t)(r - S_TXT) * D_MODEL;
    int tid = threadIdx.x;
#pragma unroll
    for (int i = 0; i < 3; ++i) {
        int c = tid * 2 + 512 * i;
        float v0 = 0.f, v1 = 0.f;
#pragma unroll
        for (int s = 0; s < NS; ++s) {
            const bf16_t* ps = (s == 2) ? p_alt : p + (size_t)s * S_TOT * D_MODEL;
            bf16x2 t2 = *(const bf16x2*)&ps[(size_t)r * D_MODEL + c];
            v0 += (float)t2[0];
            v1 += (float)t2[1];
        }
        float2 o;
        o.x = resid[c]     + gate[c]     * (v0 + bias[c]);
        o.y = resid[c + 1] + gate[c + 1] * (v1 + bias[c + 1]);
        *(float2*)&out[(size_t)r * D_MODEL + c] = o;
    }
}

// ---------------------------------------------------------------------------
// QKV epilogue: RMS-norm(q,k) + RoPE + fold 1/sqrt(DH) into q; bf16 in/out.
// ---------------------------------------------------------------------------
__global__ __launch_bounds__(128)
void qkv_epi(const bf16_t* __restrict__ qkv, const float* __restrict__ rope,
             const float* __restrict__ qn_i, const float* __restrict__ kn_i,
             const float* __restrict__ qn_t, const float* __restrict__ kn_t,
             bf16_t* __restrict__ qb, bf16_t* __restrict__ kb) {
    int h = blockIdx.x, s = blockIdx.y, dh = threadIdx.x;
    bool txt = s < S_TXT;
    const float* qn = txt ? qn_t : qn_i;
    const float* kn = txt ? kn_t : kn_i;
    const bf16_t* base = qkv + (size_t)s * 4608 + h * DHD + dh;
    float q = (float)base[0];
    float k = (float)base[D_MODEL];
    float qs = q * q, ks = k * k;
#pragma unroll
    for (int off = 32; off > 0; off >>= 1) {
        qs += __shfl_down(qs, off);
        ks += __shfl_down(ks, off);
    }
    __shared__ float red[4];
    if ((threadIdx.x & 63) == 0) {
        red[(threadIdx.x >> 6) * 2]     = qs;
        red[(threadIdx.x >> 6) * 2 + 1] = ks;
    }
    __syncthreads();
    float qr = rsqrtf((red[0] + red[2]) * (1.0f / DHD) + 1e-6f);
    float kr = rsqrtf((red[1] + red[3]) * (1.0f / DHD) + 1e-6f);
    q = q * qr * qn[dh];
    k = k * kr * kn[dh];
    int i = dh & 1, d = dh >> 1;
    const float* rp = rope + ((size_t)s * 64 + d) * 4 + i * 2;
    float r0 = rp[0], r1 = rp[1];
    float qo = __shfl_xor(q, 1), ko = __shfl_xor(k, 1);
    float q0 = i ? qo : q, q1 = i ? q : qo;
    float k0 = i ? ko : k, k1 = i ? k : ko;
    float qq = r0 * q0 + r1 * q1;
    float kk = r0 * k0 + r1 * k1;
    size_t idx = ((size_t)h * S_TOT + s) * DHD + dh;
    qb[idx] = (bf16_t)(qq * 0.08838834764831845f);  // 1/sqrt(128)
    kb[idx] = (bf16_t)kk;
}

// ---------------------------------------------------------------------------
// V transpose: per-head vT[DH][S] bf16. grid (12, 24), block 256.
// ---------------------------------------------------------------------------
__global__ __launch_bounds__(256)
void v_tr(const bf16_t* __restrict__ qkv, bf16_t* __restrict__ vt) {
    __shared__ bf16_t tile[64][130];
    int h = blockIdx.x, sb = blockIdx.y * 64;
    int tid = threadIdx.x;
#pragma unroll
    for (int j = 0; j < 32; ++j) {
        int linear = tid + 256 * j;
        int sl = linear >> 7, dh = linear & 127;
        tile[sl][dh] = qkv[(size_t)(sb + sl) * 4608 + 2 * D_MODEL + h * DHD + dh];
    }
    __syncthreads();
#pragma unroll
    for (int j = 0; j < 32; ++j) {
        int linear = tid + 256 * j;
        int dh = linear >> 6, sl = linear & 63;
        vt[((size_t)h * DHD + dh) * S_TOT + sb + sl] = tile[sl][dh];
    }
}

// ---------------------------------------------------------------------------
// Flash attention, KV-split, SINGLE-buffer LDS K/V (40 KB -> 4 blocks/CU).
// grid (12,24,KVSPLIT), 4 waves x 16 q-rows. 2 barriers per KV-tile.
// ---------------------------------------------------------------------------
__global__ __launch_bounds__(256)
void attn_k(const bf16_t* __restrict__ qbuf, const bf16_t* __restrict__ kbuf,
            const bf16_t* __restrict__ vt,
            float* __restrict__ part_o, float* __restrict__ part_ml) {
    __shared__ bf16_t Ks[64 * 128];
    __shared__ bf16_t Vs[128 * 64];
    __shared__ bf16_t P[4][16 * 64];
    int h = blockIdx.x, qblk = blockIdx.y, z = blockIdx.z;
    int q0 = qblk * 64;
    int tid = threadIdx.x, wave = tid >> 6, lane = tid & 63;
    int lr = lane & 15, lg = lane >> 4;

    const bf16_t* Qp = qbuf + ((size_t)h * S_TOT + q0 + wave * 16 + lr) * DHD;
    bf16x8 qf[4];
#pragma unroll
    for (int kk = 0; kk < 4; ++kk) qf[kk] = *(const bf16x8*)(Qp + (kk * 4 + lg) * 8);

    const int sKr = wave * 4 + (lane >> 4);
    const int cK = lane & 15;
    const bf16_t* Kb = kbuf + ((size_t)h * S_TOT + sKr) * DHD + ((cK ^ (sKr & 7)) * 8);
    const int sVr = wave * 8 + (lane >> 3);
    const int cV = lane & 7;
    const bf16_t* Vb = vt + ((size_t)h * DHD + sVr) * S_TOT + ((cV ^ (sVr & 7)) * 8);
    const int ldsV = (wave * 8) * 64;

    f32x4 of[8] = {};
    float m[4] = {-1e30f, -1e30f, -1e30f, -1e30f};
    float l[4] = {};
    const int kv0 = z * (S_TOT / KVSPLIT);
    const int nt = (S_TOT / KVSPLIT) / 64;

    for (int t = 0; t < nt; ++t) {
        const int kb0 = kv0 + t * 64;
#pragma unroll
        for (int j = 0; j < 4; ++j) {
            gload16(Kb + (size_t)(kb0 + j * 16) * DHD, &Ks[(wave * 4) * 128 + j * 2048]);
            gload16(Vb + kb0 + (size_t)j * 32 * S_TOT, &Vs[ldsV + j * 2048]);
        }
        asm volatile("s_waitcnt vmcnt(0)" ::: "memory");
        __builtin_amdgcn_s_barrier();          // K/V tile ready
        f32x4 sf[4] = {};
        __builtin_amdgcn_s_setprio(1);
#pragma unroll
        for (int n = 0; n < 4; ++n) {
#pragma unroll
            for (int kk = 0; kk < 4; ++kk) {
                bf16x8 kf = *(const bf16x8*)&Ks[(n * 16 + lr) * 128 + (((kk * 4 + lg) ^ (lr & 7)) * 8)];
                sf[n] = __builtin_amdgcn_mfma_f32_16x16x32_bf16(qf[kk], kf, sf[n], 0, 0, 0);
            }
        }
        __builtin_amdgcn_s_setprio(0);
        float bm[4], alpha[4], rs[4];
#pragma unroll
        for (int r = 0; r < 4; ++r)
            bm[r] = fmaxf(fmaxf(sf[0][r], sf[1][r]), fmaxf(sf[2][r], sf[3][r]));
#pragma unroll
        for (int mask = 1; mask < 16; mask <<= 1)
#pragma unroll
            for (int r = 0; r < 4; ++r) bm[r] = fmaxf(bm[r], __shfl_xor(bm[r], mask));
#pragma unroll
        for (int r = 0; r < 4; ++r) {
            float mn = fmaxf(m[r], bm[r]);
            alpha[r] = __expf(m[r] - mn);
            m[r] = mn;
            rs[r] = 0.f;
        }
#pragma unroll
        for (int n = 0; n < 4; ++n)
#pragma unroll
            for (int r = 0; r < 4; ++r) {
                float p = __expf(sf[n][r] - m[r]);
                rs[r] += p;
                int row = lg * 4 + r, col = n * 16 + lr;
                P[wave][row * 64 + ((((col >> 3) ^ (row & 7)) << 3) | (col & 7))] = (bf16_t)p;
            }
#pragma unroll
        for (int mask = 1; mask < 16; mask <<= 1)
#pragma unroll
            for (int r = 0; r < 4; ++r) rs[r] += __shfl_xor(rs[r], mask);
#pragma unroll
        for (int r = 0; r < 4; ++r) l[r] = l[r] * alpha[r] + rs[r];
#pragma unroll
        for (int nf = 0; nf < 8; ++nf)
#pragma unroll
            for (int r = 0; r < 4; ++r) of[nf][r] *= alpha[r];
        __builtin_amdgcn_s_setprio(1);
#pragma unroll
        for (int kk2 = 0; kk2 < 2; ++kk2) {
            bf16x8 pf = *(const bf16x8*)&P[wave][lr * 64 + (((kk2 * 4 + lg) ^ (lr & 7)) * 8)];
#pragma unroll
            for (int nf = 0; nf < 8; ++nf) {
                bf16x8 vf = *(const bf16x8*)&Vs[(nf * 16 + lr) * 64 + (((kk2 * 4 + lg) ^ (lr & 7)) * 8)];
                of[nf] = __builtin_amdgcn_mfma_f32_16x16x32_bf16(pf, vf, of[nf], 0, 0, 0);
            }
        }
        __builtin_amdgcn_s_setprio(0);
        __builtin_amdgcn_s_barrier();          // all waves done reading K/V
    }
    int hqb = h * 24 + qblk;
    float* po = part_o + ((size_t)z * HQB + hqb) * 8192;
    int rb = wave * 16 + lg * 4;
#pragma unroll
    for (int r = 0; r < 4; ++r)
#pragma unroll
        for (int nf = 0; nf < 8; ++nf)
            po[(rb + r) * 128 + nf * 16 + lr] = of[nf][r];
    if (lr == 0) {
#pragma unroll
        for (int r = 0; r < 4; ++r) {
            size_t mi = (((size_t)z * HQB + hqb) * 64 + rb + r) * 2;
            part_ml[mi]     = m[r];
            part_ml[mi + 1] = l[r];
        }
    }
}

// ---------------------------------------------------------------------------
// KV-split reduce: combine KVSPLIT partials -> bf16 o (S, D). grid 288 x 256.
// ---------------------------------------------------------------------------
__global__ __launch_bounds__(256)
void attn_red(const float* __restrict__ part_o, const float* __restrict__ part_ml,
              bf16_t* __restrict__ o) {
    int hqb = blockIdx.x;
    int h = hqb / 24, q0 = (hqb % 24) * 64;
    __shared__ float wz[KVSPLIT][64];
    __shared__ float invL[64];
    int tid = threadIdx.x;
    if (tid < 64) {
        float mz[KVSPLIT], lz[KVSPLIT];
#pragma unroll
        for (int zz = 0; zz < KVSPLIT; ++zz) {
            size_t mi = (((size_t)zz * HQB + hqb) * 64 + tid) * 2;
            mz[zz] = part_ml[mi];
            lz[zz] = part_ml[mi + 1];
        }
        float M = mz[0];
#pragma unroll
        for (int zz = 1; zz < KVSPLIT; ++zz) M = fmaxf(M, mz[zz]);
        float L = 0.f;
#pragma unroll
        for (int zz = 0; zz < KVSPLIT; ++zz) {
            float w = __expf(mz[zz] - M);
            wz[zz][tid] = w;
            L += w * lz[zz];
        }
        invL[tid] = 1.0f / L;
    }
    __syncthreads();
#pragma unroll
    for (int i = 0; i < 8; ++i) {
        int e4 = tid + 256 * i;
        int row = e4 >> 5, c4 = e4 & 31;
        f32x4 acc = {};
#pragma unroll
        for (int zz = 0; zz < KVSPLIT; ++zz) {
            f32x4 v = *(const f32x4*)&part_o[((size_t)zz * HQB + hqb) * 8192 + row * 128 + c4 * 4];
            float w = wz[zz][row];
            acc[0] += v[0] * w; acc[1] += v[1] * w; acc[2] += v[2] * w; acc[3] += v[3] * w;
        }
        float il = invL[row];
        bf16x4 r;
        r[0] = (bf16_t)(acc[0] * il); r[1] = (bf16_t)(acc[1] * il);
        r[2] = (bf16_t)(acc[2] * il); r[3] = (bf16_t)(acc[3] * il);
        *(bf16x4*)&o[(size_t)(q0 + row) * D_MODEL + h * DHD + c4 * 4] = r;
    }
}

// ---------------------------------------------------------------------------
extern "C" void kernel_launch(void* const* d_in, const int* in_sizes, int n_in,
                              void* d_out, int out_size, void* d_ws, size_t ws_size,
                              hipStream_t stream) {
    const float* hidden  = (const float*)d_in[0];
    const float* encoder = (const float*)d_in[1];
    const float* temb    = (const float*)d_in[2];
    const float* rope    = (const float*)d_in[3];
    const float* adaln_img_w = (const float*)d_in[4];
    const float* adaln_img_b = (const float*)d_in[5];
    const float* adaln_txt_w = (const float*)d_in[6];
    const float* adaln_txt_b = (const float*)d_in[7];
    const float* qkv_img_w = (const float*)d_in[8];
    const float* qkv_img_b = (const float*)d_in[9];
    const float* qkv_txt_w = (const float*)d_in[10];
    const float* qkv_txt_b = (const float*)d_in[11];
    const float* qn_img = (const float*)d_in[12];
    const float* kn_img = (const float*)d_in[13];
    const float* qn_txt = (const float*)d_in[14];
    const float* kn_txt = (const float*)d_in[15];
    const float* out_img_w = (const float*)d_in[16];
    const float* out_img_b = (const float*)d_in[17];
    const float* out_txt_w = (const float*)d_in[18];
    const float* out_txt_b = (const float*)d_in[19];
    const float* mlp_img_w1 = (const float*)d_in[20];
    const float* mlp_img_b1 = (const float*)d_in[21];
    const float* mlp_img_w2 = (const float*)d_in[22];
    const float* mlp_img_b2 = (const float*)d_in[23];
    const float* mlp_txt_w1 = (const float*)d_in[24];
    const float* mlp_txt_b1 = (const float*)d_in[25];
    const float* mlp_txt_w2 = (const float*)d_in[26];
    const float* mlp_txt_b2 = (const float*)d_in[27];
    float* dout = (float*)d_out;
    char* wsb = (char*)d_ws;

    // ws layout (byte offsets), total 70,852,608 B = 67.6 MB.
    float*  emb_i = (float*)(wsb);                    // 9216 f32
    float*  emb_t = (float*)(wsb + 36864);            // 9216 f32
    bf16_t* wreg  = (bf16_t*)(wsb + 73728);           // 37.75 MB (weights, reused per stage)
    float*  part  = (float*)(wsb + 73728);            // adaln partials overlay
    float*  part_o = (float*)(wsb + 73728);           // attn partial O overlay (37.7 MB)
    bf16_t* n1    = (bf16_t*)(wsb + 37822464);        // 1536x1536 bf16 (LN1, later LN2)
    float*  part_ml = (float*)(wsb + 37822464);       // attn (m,l) overlay (n1 dead there)
    bf16_t* qkvb  = (bf16_t*)(wsb + 42541056);        // 1536x4608 bf16
    bf16_t* obuf  = qkvb;                             // alias (qkvb dead after epi/v_tr)
    bf16_t* ffb   = qkvb + 2359296;                   // 1536x6144 bf16 (byte 47259648)
    bf16_t* qb    = (bf16_t*)(wsb + 56696832);        // 12x1536x128 bf16
    bf16_t* kb    = (bf16_t*)(wsb + 61415424);
    bf16_t* vt    = (bf16_t*)(wsb + 66134016);
    // K-split partial overlays (bf16 [z][1536][1536], 4,718,592 B each):
    bf16_t* pout = (bf16_t*)(wsb + 47259648);  // out-proj z=0,1 (ffb head; dead until MLP1)
    bf16_t* pm2  = (bf16_t*)(wsb + 37822464);  // MLP2 z=0,1 (n1+obuf; dead at MLP2)
    bf16_t* pm2b = (bf16_t*)(wsb + 66134016);  // MLP2 z=2 (vt; dead after attn)

    // 1. adaLN (K-split + reduce)
    adaln_p<<<dim3(72, 8), 256, 0, stream>>>(temb, adaln_img_w, adaln_txt_w, part);
    adaln_r<<<72, 256, 0, stream>>>(part, adaln_img_b, adaln_txt_b, emb_i, emb_t);
    // 2. LN1 + modulate -> bf16
    ln_mod<<<S_TOT, 256, 0, stream>>>(encoder, hidden, emb_t, emb_i, 0, 1, n1);
    // 3. QKV (864 blocks)
    conv_wt<1536, 4608><<<dim3(72, 24, 2), 256, 0, stream>>>(qkv_txt_w, qkv_img_w, wreg);
    gemmU<0, bf16_t><<<dim3(72, 12), 256, 0, stream>>>(
        n1, D_MODEL, wreg, 1536, 4608 * 1536, qkv_txt_b, qkv_img_b,
        nullptr, nullptr, 0, nullptr, nullptr, qkvb, nullptr, 4608, 1536);
    // 4. RMS + RoPE -> bf16 q,k ; V transpose
    qkv_epi<<<dim3(12, 1536), 128, 0, stream>>>(qkvb, rope, qn_img, kn_img, qn_txt, kn_txt, qb, kb);
    v_tr<<<dim3(12, 24), 256, 0, stream>>>(qkvb, vt);
    // 5. attention (KV-split, single-buffer LDS) + reduce -> o bf16
    attn_k<<<dim3(12, 24, KVSPLIT), 256, 0, stream>>>(qb, kb, vt, part_o, part_ml);
    attn_red<<<HQB, 256, 0, stream>>>(part_o, part_ml, obuf);
    // 6. out-proj: K-split x2 (576 blocks) + fused reduce epilogue
    conv_wt<1536, 1536><<<dim3(24, 24, 2), 256, 0, stream>>>(out_txt_w, out_img_w, wreg);
    gemmU<3, bf16_t><<<dim3(24, 12, 2), 256, 0, stream>>>(
        obuf, D_MODEL, wreg, 1536, 1536 * 1536, nullptr, nullptr,
        nullptr, nullptr, 0, nullptr, nullptr, pout, nullptr, D_MODEL, 768);
    gemm_red<2><<<S_TOT, 256, 0, stream>>>(
        pout, nullptr, out_txt_b, out_img_b,
        emb_t + 2 * D_MODEL, emb_i + 2 * D_MODEL, encoder, hidden, dout);
    // 7. LN2 + modulate -> bf16
    ln_mod<<<S_TOT, 256, 0, stream>>>(dout, dout + (size_t)S_TXT * D_MODEL, emb_t, emb_i, 3, 4, n1);
    // 8. MLP up + gelu -> bf16 ff (1152 blocks)
    conv_wt<1536, 6144><<<dim3(96, 24, 2), 256, 0, stream>>>(mlp_txt_w1, mlp_img_w1, wreg);
    gemmU<1, bf16_t><<<dim3(96, 12), 256, 0, stream>>>(
        n1, D_MODEL, wreg, 1536, 6144 * 1536, mlp_txt_b1, mlp_img_b1,
        nullptr, nullptr, 0, nullptr, nullptr, ffb, nullptr, FF_DIM, 1536);
    // 9. MLP down: K-split x3 (864 blocks) + fused reduce epilogue (in-place)
    conv_wt<6144, 1536><<<dim3(24, 96, 2), 256, 0, stream>>>(mlp_txt_w2, mlp_img_w2, wreg);
    gemmU<3, bf16_t><<<dim3(24, 12, 3), 256, 0, stream>>>(
        ffb, FF_DIM, wreg, 6144, 1536 * 6144, nullptr, nullptr,
        nullptr, nullptr, 0, nullptr, nullptr, pm2, pm2b, D_MODEL, 2048);
    gemm_red<3><<<S_TOT, 256, 0, stream>>>(
        pm2, pm2b, mlp_txt_b2, mlp_img_b2,
        emb_t + 5 * D_MODEL, emb_i + 5 * D_MODEL,
        dout, dout + (size_t)S_TXT * D_MODEL, dout);
    (void)in_sizes; (void)n_in; (void)out_size; (void)ws_size;
}

// Round 13
// 343.444 us; speedup vs baseline: 1.0390x; 1.0390x over previous
//
#include <hip/hip_runtime.h>
#include <hip/hip_bf16.h>

typedef __bf16 bf16_t;
typedef __attribute__((ext_vector_type(4))) float f32x4;
typedef __attribute__((ext_vector_type(8))) bf16_t bf16x8;
typedef __attribute__((ext_vector_type(4))) bf16_t bf16x4;
typedef __attribute__((ext_vector_type(2))) bf16_t bf16x2;

#define D_MODEL 1536
#define NH 12
#define DHD 128
#define S_TXT 512
#define S_TOT 1536
#define FF_DIM 6144
#define KVSPLIT 4
#define HQB 288   // 12 heads * 24 q-blocks

// async global->LDS, 16 B per lane. LDS dest is wave-uniform base (+lane*16 by HW).
__device__ inline void gload16(const void* g, void* l) {
    __builtin_amdgcn_global_load_lds((const __attribute__((address_space(1))) unsigned int*)g,
                                     (__attribute__((address_space(3))) unsigned int*)l, 16, 0, 0);
}

// ---------------------------------------------------------------------------
// adaLN stage 1: partial dot products, K split 8 ways. grid (72,8) block 256.
// ---------------------------------------------------------------------------
__global__ __launch_bounds__(256)
void adaln_p(const float* __restrict__ temb,
             const float* __restrict__ w_img, const float* __restrict__ w_txt,
             float* __restrict__ part) {
    __shared__ float t[192];
    int tid = threadIdx.x;
    int k0 = blockIdx.y * 192;
    if (tid < 192) {
        float x = temb[k0 + tid];
        t[tid] = x / (1.0f + __expf(-x));
    }
    __syncthreads();
    int n_g = blockIdx.x * 256 + tid;
    bool img = n_g < 9216;
    const float* W = img ? w_img : w_txt;
    int n = img ? n_g : n_g - 9216;
    float acc = 0.f;
    for (int kk = 0; kk < 192; kk += 4) {
        acc += t[kk]     * W[(size_t)(k0 + kk) * 9216 + n];
        acc += t[kk + 1] * W[(size_t)(k0 + kk + 1) * 9216 + n];
        acc += t[kk + 2] * W[(size_t)(k0 + kk + 2) * 9216 + n];
        acc += t[kk + 3] * W[(size_t)(k0 + kk + 3) * 9216 + n];
    }
    part[(size_t)blockIdx.y * 18432 + n_g] = acc;
}

// adaLN stage 2: reduce + bias. grid 72 x 256.
__global__ __launch_bounds__(256)
void adaln_r(const float* __restrict__ part,
             const float* __restrict__ b_img, const float* __restrict__ b_txt,
             float* __restrict__ emb_img, float* __restrict__ emb_txt) {
    int n_g = blockIdx.x * 256 + threadIdx.x;
    float a = 0.f;
#pragma unroll
    for (int kc = 0; kc < 8; ++kc) a += part[(size_t)kc * 18432 + n_g];
    if (n_g < 9216) emb_img[n_g] = a + b_img[n_g];
    else            emb_txt[n_g - 9216] = a + b_txt[n_g - 9216];
}

// ---------------------------------------------------------------------------
// LayerNorm + modulate -> bf16. Rows 0..511 txt, 512..1535 img.
// ---------------------------------------------------------------------------
__global__ __launch_bounds__(256)
void ln_mod(const float* __restrict__ src_txt, const float* __restrict__ src_img,
            const float* __restrict__ emb_t, const float* __restrict__ emb_i,
            int sh_c, int sc_c, bf16_t* __restrict__ out) {
    int row = blockIdx.x;
    bool txt = row < S_TXT;
    const float* src = txt ? src_txt + (size_t)row * D_MODEL
                           : src_img + (size_t)(row - S_TXT) * D_MODEL;
    const float* emb = txt ? emb_t : emb_i;
    int tid = threadIdx.x;
    float2 v[3];
    float s = 0.f, sq = 0.f;
#pragma unroll
    for (int i = 0; i < 3; ++i) {
        v[i] = *(const float2*)(src + tid * 2 + 512 * i);
        s  += v[i].x + v[i].y;
        sq += v[i].x * v[i].x + v[i].y * v[i].y;
    }
#pragma unroll
    for (int off = 32; off > 0; off >>= 1) {
        s  += __shfl_down(s, off);
        sq += __shfl_down(sq, off);
    }
    __shared__ float red[8];
    int wave = tid >> 6, lane = tid & 63;
    if (lane == 0) { red[wave] = s; red[4 + wave] = sq; }
    __syncthreads();
    float ts = red[0] + red[1] + red[2] + red[3];
    float tq = red[4] + red[5] + red[6] + red[7];
    float mean = ts * (1.0f / D_MODEL);
    float var  = tq * (1.0f / D_MODEL) - mean * mean;
    float rstd = rsqrtf(var + 1e-6f);
    bf16_t* op = out + (size_t)row * D_MODEL;
#pragma unroll
    for (int i = 0; i < 3; ++i) {
        int c0 = tid * 2 + 512 * i;
        bf16x2 r;
        r[0] = (bf16_t)((v[i].x - mean) * rstd * (1.0f + emb[sc_c * D_MODEL + c0])     + emb[sh_c * D_MODEL + c0]);
        r[1] = (bf16_t)((v[i].y - mean) * rstd * (1.0f + emb[sc_c * D_MODEL + c0 + 1]) + emb[sh_c * D_MODEL + c0 + 1]);
        *(bf16x2*)(op + c0) = r;
    }
}

// ---------------------------------------------------------------------------
// Weight convert+transpose: W f32 [K][N] -> Wt bf16 [N][K]. grid (N/64,K/64,2).
// ---------------------------------------------------------------------------
template <int K, int N>
__global__ __launch_bounds__(256)
void conv_wt(const float* __restrict__ w_t, const float* __restrict__ w_i,
             bf16_t* __restrict__ dst) {
    __shared__ float tile[64][65];
    const float* src = blockIdx.z ? w_i : w_t;
    bf16_t* d = dst + (size_t)blockIdx.z * N * K;
    int bn = blockIdx.x * 64, bk = blockIdx.y * 64;
    int tid = threadIdx.x;
#pragma unroll
    for (int j = 0; j < 4; ++j) {
        int k = (tid >> 4) + 16 * j, c4 = tid & 15;
        float4 v = *(const float4*)(src + (size_t)(bk + k) * N + bn + c4 * 4);
        tile[k][c4 * 4 + 0] = v.x;
        tile[k][c4 * 4 + 1] = v.y;
        tile[k][c4 * 4 + 2] = v.z;
        tile[k][c4 * 4 + 3] = v.w;
    }
    __syncthreads();
#pragma unroll
    for (int j = 0; j < 4; ++j) {
        int n = (tid >> 4) + 16 * j, k4 = tid & 15;
        bf16x4 o;
        o[0] = (bf16_t)tile[k4 * 4 + 0][n];
        o[1] = (bf16_t)tile[k4 * 4 + 1][n];
        o[2] = (bf16_t)tile[k4 * 4 + 2][n];
        o[3] = (bf16_t)tile[k4 * 4 + 3][n];
        *(bf16x4*)(d + (size_t)(bn + n) * K + bk + k4 * 4) = o;
    }
}

// ---------------------------------------------------------------------------
// gemmU (R10 version): 128x64 tile, BK=64, 4 waves, single-buffer 24 KB LDS.
// Used for QKV and out-proj. L2 supertile swizzle; 8-chunk XOR (2-way free).
// EPI: 0=bias(bf16) 3=raw partial (bf16, z-th partial at out + z*1536*ldo).
// ---------------------------------------------------------------------------
template <int EPI, typename OutT>
__global__ __launch_bounds__(256)
void gemmU(const bf16_t* __restrict__ A, int lda,
           const bf16_t* __restrict__ Wt, int ldw, int wimg_off,
           const float* __restrict__ bias_t, const float* __restrict__ bias_i,
           OutT* __restrict__ out, int ldo, int Ks) {
    __shared__ bf16_t As[128 * 64];
    __shared__ bf16_t Bs[64 * 64];
    const int tid = threadIdx.x;

    const int nbx = gridDim.x, nby = gridDim.y;
    const int nwg = nbx * nby;
    const int lb0 = blockIdx.y * nbx + blockIdx.x;
    int bmT, bnT;
    if (nby == 12 && (nbx & 3) == 0 && (nwg & 7) == 0) {
        const int CC = nbx >> 2;
        const int xcd = lb0 & 7, c = lb0 >> 3;
        bmT = (xcd & 1) * 6 + (c % 6);
        bnT = (xcd >> 1) * CC + (c / 6);
    } else {
        int lb = lb0;
        if ((nwg & 7) == 0) lb = (lb & 7) * (nwg >> 3) + (lb >> 3);
        bmT = lb / nbx; bnT = lb % nbx;
    }
    const int bm = bmT * 128, bn = bnT * 64;
    const int koff = blockIdx.z * Ks;

    const bool txt = bm < S_TXT;
    const bf16_t* W = txt ? Wt : Wt + wimg_off;
    const float* bias = txt ? bias_t : bias_i;
    const int wave = tid >> 6, lane = tid & 63;
    const int wr = (wave >> 1) * 64, wc = (wave & 1) * 32;
    const int lr = lane & 15, lg = lane >> 4;

    const int srow = wave * 8 + (lane >> 3);
    const int csrc = ((lane & 7) ^ ((lane >> 3) & 7)) * 8;
    const bf16_t* Ab = A + (size_t)(bm + srow) * lda + koff + csrc;
    const bf16_t* Wb = W + (size_t)(bn + srow) * ldw + koff + csrc;
    const int ldst = (wave * 8) * 64;

    f32x4 acc[4][2] = {};
    const int nt = Ks >> 6;

    for (int t = 0; t < nt; ++t) {
#pragma unroll
        for (int j = 0; j < 4; ++j)
            gload16(Ab + (size_t)j * 32 * lda + t * 64, &As[ldst + j * 2048]);
#pragma unroll
        for (int j = 0; j < 2; ++j)
            gload16(Wb + (size_t)j * 32 * ldw + t * 64, &Bs[ldst + j * 2048]);
        __syncthreads();
#pragma unroll
        for (int kk = 0; kk < 2; ++kk) {
            bf16x8 af[4], bfm[2];
#pragma unroll
            for (int m = 0; m < 4; ++m) {
                int rr = wr + m * 16 + lr;
                af[m] = *(const bf16x8*)&As[rr * 64 + (((kk * 4 + lg) ^ (lr & 7)) * 8)];
            }
#pragma unroll
            for (int n = 0; n < 2; ++n) {
                int rr = wc + n * 16 + lr;
                bfm[n] = *(const bf16x8*)&Bs[rr * 64 + (((kk * 4 + lg) ^ (lr & 7)) * 8)];
            }
#pragma unroll
            for (int m = 0; m < 4; ++m)
#pragma unroll
                for (int n = 0; n < 2; ++n)
                    acc[m][n] = __builtin_amdgcn_mfma_f32_16x16x32_bf16(af[m], bfm[n], acc[m][n], 0, 0, 0);
        }
        __syncthreads();
    }

    OutT* obase = out;
    if constexpr (EPI == 3) obase = out + (size_t)blockIdx.z * S_TOT * ldo;
#pragma unroll
    for (int m = 0; m < 4; ++m) {
#pragma unroll
        for (int r = 0; r < 4; ++r) {
            int grow = bm + wr + m * 16 + lg * 4 + r;
#pragma unroll
            for (int n = 0; n < 2; ++n) {
                int gcol = bn + wc + n * 16 + lr;
                float v = acc[m][n][r];
                if constexpr (EPI != 3) v += bias[gcol];
                obase[(size_t)grow * ldo + gcol] = (OutT)v;
            }
        }
    }
}

// ---------------------------------------------------------------------------
// gemmV: 128x128 tile, BK=64, 4 waves (2x2), wave = 64x64 output (4x4 frags,
// 64 acc VGPR) -> LDS read bytes/FLOP cut 33% vs gemmU. Single-buffer 32 KB
// LDS, m97 2-barrier loop, supertile swizzle (nby==12 assumed).
// EPI: 1=bias+gelu(bf16) 3=raw partial (z<2 -> out+z*slot, z>=2 -> out_alt).
// ---------------------------------------------------------------------------
template <int EPI>
__global__ __launch_bounds__(256)
void gemmV(const bf16_t* __restrict__ A, int lda,
           const bf16_t* __restrict__ Wt, int ldw, int wimg_off,
           const float* __restrict__ bias_t, const float* __restrict__ bias_i,
           bf16_t* __restrict__ out, bf16_t* __restrict__ out_alt, int ldo, int Ks) {
    __shared__ bf16_t As[128 * 64];
    __shared__ bf16_t Bs[128 * 64];
    const int tid = threadIdx.x;

    const int nbx = gridDim.x;
    const int lb0 = blockIdx.y * nbx + blockIdx.x;
    const int CC = nbx >> 2;
    const int xcd = lb0 & 7, c = lb0 >> 3;
    const int bmT = (xcd & 1) * 6 + (c % 6);
    const int bnT = (xcd >> 1) * CC + (c / 6);
    const int bm = bmT * 128, bn = bnT * 128;
    const int koff = blockIdx.z * Ks;

    const bool txt = bm < S_TXT;
    const bf16_t* W = txt ? Wt : Wt + wimg_off;
    const float* bias = txt ? bias_t : bias_i;
    const int wave = tid >> 6, lane = tid & 63;
    const int wr = (wave >> 1) * 64, wc = (wave & 1) * 64;
    const int lr = lane & 15, lg = lane >> 4;

    const int srow = wave * 8 + (lane >> 3);
    const int csrc = ((lane & 7) ^ ((lane >> 3) & 7)) * 8;
    const bf16_t* Ab = A + (size_t)(bm + srow) * lda + koff + csrc;
    const bf16_t* Wb = W + (size_t)(bn + srow) * ldw + koff + csrc;
    const int ldst = (wave * 8) * 64;

    f32x4 acc[4][4] = {};
    const int nt = Ks >> 6;

    for (int t = 0; t < nt; ++t) {
#pragma unroll
        for (int j = 0; j < 4; ++j)
            gload16(Ab + (size_t)j * 32 * lda + t * 64, &As[ldst + j * 2048]);
#pragma unroll
        for (int j = 0; j < 4; ++j)
            gload16(Wb + (size_t)j * 32 * ldw + t * 64, &Bs[ldst + j * 2048]);
        __syncthreads();   // drains vmcnt -> tiles ready
#pragma unroll
        for (int kk = 0; kk < 2; ++kk) {
            bf16x8 af[4], bfm[4];
#pragma unroll
            for (int m = 0; m < 4; ++m) {
                int rr = wr + m * 16 + lr;
                af[m] = *(const bf16x8*)&As[rr * 64 + (((kk * 4 + lg) ^ (lr & 7)) * 8)];
            }
#pragma unroll
            for (int n = 0; n < 4; ++n) {
                int rr = wc + n * 16 + lr;
                bfm[n] = *(const bf16x8*)&Bs[rr * 64 + (((kk * 4 + lg) ^ (lr & 7)) * 8)];
            }
#pragma unroll
            for (int m = 0; m < 4; ++m)
#pragma unroll
                for (int n = 0; n < 4; ++n)
                    acc[m][n] = __builtin_amdgcn_mfma_f32_16x16x32_bf16(af[m], bfm[n], acc[m][n], 0, 0, 0);
        }
        __syncthreads();   // reads done before next stage overwrites
    }

    bf16_t* obase = out;
    if constexpr (EPI == 3)
        obase = (blockIdx.z < 2) ? out + (size_t)blockIdx.z * S_TOT * ldo
                                 : out_alt + (size_t)(blockIdx.z - 2) * S_TOT * ldo;
#pragma unroll
    for (int m = 0; m < 4; ++m) {
#pragma unroll
        for (int r = 0; r < 4; ++r) {
            int grow = bm + wr + m * 16 + lg * 4 + r;
#pragma unroll
            for (int n = 0; n < 4; ++n) {
                int gcol = bn + wc + n * 16 + lr;
                float v = acc[m][n][r];
                if constexpr (EPI == 1) {
                    float x = v + bias[gcol];
                    float th = tanhf(0.7978845608028654f * (x + 0.044715f * x * x * x));
                    v = 0.5f * x * (1.0f + th);
                }
                obase[(size_t)grow * ldo + gcol] = (bf16_t)v;
            }
        }
    }
}

// ---------------------------------------------------------------------------
// K-split reduce: out = resid + gate*(bias + sum_s partial_s). grid 1536 x 256.
// partials bf16: slots 0,1 at p; slots >=2 at p_alt.
// ---------------------------------------------------------------------------
template <int NS>
__global__ __launch_bounds__(256)
void gemm_red(const bf16_t* __restrict__ p, const bf16_t* __restrict__ p_alt,
              const float* __restrict__ bias_t, const float* __restrict__ bias_i,
              const float* __restrict__ gate_t, const float* __restrict__ gate_i,
              const float* __restrict__ resid_t, const float* __restrict__ resid_i,
              float* __restrict__ out) {
    int r = blockIdx.x;
    bool txt = r < S_TXT;
    const float* bias = txt ? bias_t : bias_i;
    const float* gate = txt ? gate_t : gate_i;
    const float* resid = txt ? resid_t + (size_t)r * D_MODEL
                             : resid_i + (size_t)(r - S_TXT) * D_MODEL;
    int tid = threadIdx.x;
#pragma unroll
    for (int i = 0; i < 3; ++i) {
        int c = tid * 2 + 512 * i;
        float v0 = 0.f, v1 = 0.f;
#pragma unroll
        for (int s = 0; s < NS; ++s) {
            const bf16_t* ps = (s < 2) ? p + (size_t)s * S_TOT * D_MODEL
                                       : p_alt + (size_t)(s - 2) * S_TOT * D_MODEL;
            bf16x2 t2 = *(const bf16x2*)&ps[(size_t)r * D_MODEL + c];
            v0 += (float)t2[0];
            v1 += (float)t2[1];
        }
        float2 o;
        o.x = resid[c]     + gate[c]     * (v0 + bias[c]);
        o.y = resid[c + 1] + gate[c + 1] * (v1 + bias[c + 1]);
        *(float2*)&out[(size_t)r * D_MODEL + c] = o;
    }
}

// ---------------------------------------------------------------------------
// QKV epilogue: RMS-norm(q,k) + RoPE + fold 1/sqrt(DH) into q; bf16 in/out.
// ---------------------------------------------------------------------------
__global__ __launch_bounds__(128)
void qkv_epi(const bf16_t* __restrict__ qkv, const float* __restrict__ rope,
             const float* __restrict__ qn_i, const float* __restrict__ kn_i,
             const float* __restrict__ qn_t, const float* __restrict__ kn_t,
             bf16_t* __restrict__ qb, bf16_t* __restrict__ kb) {
    int h = blockIdx.x, s = blockIdx.y, dh = threadIdx.x;
    bool txt = s < S_TXT;
    const float* qn = txt ? qn_t : qn_i;
    const float* kn = txt ? kn_t : kn_i;
    const bf16_t* base = qkv + (size_t)s * 4608 + h * DHD + dh;
    float q = (float)base[0];
    float k = (float)base[D_MODEL];
    float qs = q * q, ks = k * k;
#pragma unroll
    for (int off = 32; off > 0; off >>= 1) {
        qs += __shfl_down(qs, off);
        ks += __shfl_down(ks, off);
    }
    __shared__ float red[4];
    if ((threadIdx.x & 63) == 0) {
        red[(threadIdx.x >> 6) * 2]     = qs;
        red[(threadIdx.x >> 6) * 2 + 1] = ks;
    }
    __syncthreads();
    float qr = rsqrtf((red[0] + red[2]) * (1.0f / DHD) + 1e-6f);
    float kr = rsqrtf((red[1] + red[3]) * (1.0f / DHD) + 1e-6f);
    q = q * qr * qn[dh];
    k = k * kr * kn[dh];
    int i = dh & 1, d = dh >> 1;
    const float* rp = rope + ((size_t)s * 64 + d) * 4 + i * 2;
    float r0 = rp[0], r1 = rp[1];
    float qo = __shfl_xor(q, 1), ko = __shfl_xor(k, 1);
    float q0 = i ? qo : q, q1 = i ? q : qo;
    float k0 = i ? ko : k, k1 = i ? k : ko;
    float qq = r0 * q0 + r1 * q1;
    float kk = r0 * k0 + r1 * k1;
    size_t idx = ((size_t)h * S_TOT + s) * DHD + dh;
    qb[idx] = (bf16_t)(qq * 0.08838834764831845f);  // 1/sqrt(128)
    kb[idx] = (bf16_t)kk;
}

// ---------------------------------------------------------------------------
// V transpose: per-head vT[DH][S] bf16. grid (12, 24), block 256.
// ---------------------------------------------------------------------------
__global__ __launch_bounds__(256)
void v_tr(const bf16_t* __restrict__ qkv, bf16_t* __restrict__ vt) {
    __shared__ bf16_t tile[64][130];
    int h = blockIdx.x, sb = blockIdx.y * 64;
    int tid = threadIdx.x;
#pragma unroll
    for (int j = 0; j < 32; ++j) {
        int linear = tid + 256 * j;
        int sl = linear >> 7, dh = linear & 127;
        tile[sl][dh] = qkv[(size_t)(sb + sl) * 4608 + 2 * D_MODEL + h * DHD + dh];
    }
    __syncthreads();
#pragma unroll
    for (int j = 0; j < 32; ++j) {
        int linear = tid + 256 * j;
        int dh = linear >> 6, sl = linear & 63;
        vt[((size_t)h * DHD + dh) * S_TOT + sb + sl] = tile[sl][dh];
    }
}

// ---------------------------------------------------------------------------
// Flash attention, KV-split, SINGLE-buffer LDS K/V (40 KB -> 4 blocks/CU).
// grid (12,24,KVSPLIT), 4 waves x 16 q-rows. 2 barriers per KV-tile.
// ---------------------------------------------------------------------------
__global__ __launch_bounds__(256)
void attn_k(const bf16_t* __restrict__ qbuf, const bf16_t* __restrict__ kbuf,
            const bf16_t* __restrict__ vt,
            float* __restrict__ part_o, float* __restrict__ part_ml) {
    __shared__ bf16_t Ks[64 * 128];
    __shared__ bf16_t Vs[128 * 64];
    __shared__ bf16_t P[4][16 * 64];
    int h = blockIdx.x, qblk = blockIdx.y, z = blockIdx.z;
    int q0 = qblk * 64;
    int tid = threadIdx.x, wave = tid >> 6, lane = tid & 63;
    int lr = lane & 15, lg = lane >> 4;

    const bf16_t* Qp = qbuf + ((size_t)h * S_TOT + q0 + wave * 16 + lr) * DHD;
    bf16x8 qf[4];
#pragma unroll
    for (int kk = 0; kk < 4; ++kk) qf[kk] = *(const bf16x8*)(Qp + (kk * 4 + lg) * 8);

    const int sKr = wave * 4 + (lane >> 4);
    const int cK = lane & 15;
    const bf16_t* Kb = kbuf + ((size_t)h * S_TOT + sKr) * DHD + ((cK ^ (sKr & 7)) * 8);
    const int sVr = wave * 8 + (lane >> 3);
    const int cV = lane & 7;
    const bf16_t* Vb = vt + ((size_t)h * DHD + sVr) * S_TOT + ((cV ^ (sVr & 7)) * 8);
    const int ldsV = (wave * 8) * 64;

    f32x4 of[8] = {};
    float m[4] = {-1e30f, -1e30f, -1e30f, -1e30f};
    float l[4] = {};
    const int kv0 = z * (S_TOT / KVSPLIT);
    const int nt = (S_TOT / KVSPLIT) / 64;

    for (int t = 0; t < nt; ++t) {
        const int kb0 = kv0 + t * 64;
#pragma unroll
        for (int j = 0; j < 4; ++j) {
            gload16(Kb + (size_t)(kb0 + j * 16) * DHD, &Ks[(wave * 4) * 128 + j * 2048]);
            gload16(Vb + kb0 + (size_t)j * 32 * S_TOT, &Vs[ldsV + j * 2048]);
        }
        asm volatile("s_waitcnt vmcnt(0)" ::: "memory");
        __builtin_amdgcn_s_barrier();          // K/V tile ready
        f32x4 sf[4] = {};
        __builtin_amdgcn_s_setprio(1);
#pragma unroll
        for (int n = 0; n < 4; ++n) {
#pragma unroll
            for (int kk = 0; kk < 4; ++kk) {
                bf16x8 kf = *(const bf16x8*)&Ks[(n * 16 + lr) * 128 + (((kk * 4 + lg) ^ (lr & 7)) * 8)];
                sf[n] = __builtin_amdgcn_mfma_f32_16x16x32_bf16(qf[kk], kf, sf[n], 0, 0, 0);
            }
        }
        __builtin_amdgcn_s_setprio(0);
        float bm[4], alpha[4], rs[4];
#pragma unroll
        for (int r = 0; r < 4; ++r)
            bm[r] = fmaxf(fmaxf(sf[0][r], sf[1][r]), fmaxf(sf[2][r], sf[3][r]));
#pragma unroll
        for (int mask = 1; mask < 16; mask <<= 1)
#pragma unroll
            for (int r = 0; r < 4; ++r) bm[r] = fmaxf(bm[r], __shfl_xor(bm[r], mask));
#pragma unroll
        for (int r = 0; r < 4; ++r) {
            float mn = fmaxf(m[r], bm[r]);
            alpha[r] = __expf(m[r] - mn);
            m[r] = mn;
            rs[r] = 0.f;
        }
#pragma unroll
        for (int n = 0; n < 4; ++n)
#pragma unroll
            for (int r = 0; r < 4; ++r) {
                float p = __expf(sf[n][r] - m[r]);
                rs[r] += p;
                int row = lg * 4 + r, col = n * 16 + lr;
                P[wave][row * 64 + ((((col >> 3) ^ (row & 7)) << 3) | (col & 7))] = (bf16_t)p;
            }
#pragma unroll
        for (int mask = 1; mask < 16; mask <<= 1)
#pragma unroll
            for (int r = 0; r < 4; ++r) rs[r] += __shfl_xor(rs[r], mask);
#pragma unroll
        for (int r = 0; r < 4; ++r) l[r] = l[r] * alpha[r] + rs[r];
#pragma unroll
        for (int nf = 0; nf < 8; ++nf)
#pragma unroll
            for (int r = 0; r < 4; ++r) of[nf][r] *= alpha[r];
        __builtin_amdgcn_s_setprio(1);
#pragma unroll
        for (int kk2 = 0; kk2 < 2; ++kk2) {
            bf16x8 pf = *(const bf16x8*)&P[wave][lr * 64 + (((kk2 * 4 + lg) ^ (lr & 7)) * 8)];
#pragma unroll
            for (int nf = 0; nf < 8; ++nf) {
                bf16x8 vf = *(const bf16x8*)&Vs[(nf * 16 + lr) * 64 + (((kk2 * 4 + lg) ^ (lr & 7)) * 8)];
                of[nf] = __builtin_amdgcn_mfma_f32_16x16x32_bf16(pf, vf, of[nf], 0, 0, 0);
            }
        }
        __builtin_amdgcn_s_setprio(0);
        __builtin_amdgcn_s_barrier();          // all waves done reading K/V
    }
    int hqb = h * 24 + qblk;
    float* po = part_o + ((size_t)z * HQB + hqb) * 8192;
    int rb = wave * 16 + lg * 4;
#pragma unroll
    for (int r = 0; r < 4; ++r)
#pragma unroll
        for (int nf = 0; nf < 8; ++nf)
            po[(rb + r) * 128 + nf * 16 + lr] = of[nf][r];
    if (lr == 0) {
#pragma unroll
        for (int r = 0; r < 4; ++r) {
            size_t mi = (((size_t)z * HQB + hqb) * 64 + rb + r) * 2;
            part_ml[mi]     = m[r];
            part_ml[mi + 1] = l[r];
        }
    }
}

// ---------------------------------------------------------------------------
// KV-split reduce: combine KVSPLIT partials -> bf16 o (S, D). grid 288 x 256.
// ---------------------------------------------------------------------------
__global__ __launch_bounds__(256)
void attn_red(const float* __restrict__ part_o, const float* __restrict__ part_ml,
              bf16_t* __restrict__ o) {
    int hqb = blockIdx.x;
    int h = hqb / 24, q0 = (hqb % 24) * 64;
    __shared__ float wz[KVSPLIT][64];
    __shared__ float invL[64];
    int tid = threadIdx.x;
    if (tid < 64) {
        float mz[KVSPLIT], lz[KVSPLIT];
#pragma unroll
        for (int zz = 0; zz < KVSPLIT; ++zz) {
            size_t mi = (((size_t)zz * HQB + hqb) * 64 + tid) * 2;
            mz[zz] = part_ml[mi];
            lz[zz] = part_ml[mi + 1];
        }
        float M = mz[0];
#pragma unroll
        for (int zz = 1; zz < KVSPLIT; ++zz) M = fmaxf(M, mz[zz]);
        float L = 0.f;
#pragma unroll
        for (int zz = 0; zz < KVSPLIT; ++zz) {
            float w = __expf(mz[zz] - M);
            wz[zz][tid] = w;
            L += w * lz[zz];
        }
        invL[tid] = 1.0f / L;
    }
    __syncthreads();
#pragma unroll
    for (int i = 0; i < 8; ++i) {
        int e4 = tid + 256 * i;
        int row = e4 >> 5, c4 = e4 & 31;
        f32x4 acc = {};
#pragma unroll
        for (int zz = 0; zz < KVSPLIT; ++zz) {
            f32x4 v = *(const f32x4*)&part_o[((size_t)zz * HQB + hqb) * 8192 + row * 128 + c4 * 4];
            float w = wz[zz][row];
            acc[0] += v[0] * w; acc[1] += v[1] * w; acc[2] += v[2] * w; acc[3] += v[3] * w;
        }
        float il = invL[row];
        bf16x4 r;
        r[0] = (bf16_t)(acc[0] * il); r[1] = (bf16_t)(acc[1] * il);
        r[2] = (bf16_t)(acc[2] * il); r[3] = (bf16_t)(acc[3] * il);
        *(bf16x4*)&o[(size_t)(q0 + row) * D_MODEL + h * DHD + c4 * 4] = r;
    }
}

// ---------------------------------------------------------------------------
extern "C" void kernel_launch(void* const* d_in, const int* in_sizes, int n_in,
                              void* d_out, int out_size, void* d_ws, size_t ws_size,
                              hipStream_t stream) {
    const float* hidden  = (const float*)d_in[0];
    const float* encoder = (const float*)d_in[1];
    const float* temb    = (const float*)d_in[2];
    const float* rope    = (const float*)d_in[3];
    const float* adaln_img_w = (const float*)d_in[4];
    const float* adaln_img_b = (const float*)d_in[5];
    const float* adaln_txt_w = (const float*)d_in[6];
    const float* adaln_txt_b = (const float*)d_in[7];
    const float* qkv_img_w = (const float*)d_in[8];
    const float* qkv_img_b = (const float*)d_in[9];
    const float* qkv_txt_w = (const float*)d_in[10];
    const float* qkv_txt_b = (const float*)d_in[11];
    const float* qn_img = (const float*)d_in[12];
    const float* kn_img = (const float*)d_in[13];
    const float* qn_txt = (const float*)d_in[14];
    const float* kn_txt = (const float*)d_in[15];
    const float* out_img_w = (const float*)d_in[16];
    const float* out_img_b = (const float*)d_in[17];
    const float* out_txt_w = (const float*)d_in[18];
    const float* out_txt_b = (const float*)d_in[19];
    const float* mlp_img_w1 = (const float*)d_in[20];
    const float* mlp_img_b1 = (const float*)d_in[21];
    const float* mlp_img_w2 = (const float*)d_in[22];
    const float* mlp_img_b2 = (const float*)d_in[23];
    const float* mlp_txt_w1 = (const float*)d_in[24];
    const float* mlp_txt_b1 = (const float*)d_in[25];
    const float* mlp_txt_w2 = (const float*)d_in[26];
    const float* mlp_txt_b2 = (const float*)d_in[27];
    float* dout = (float*)d_out;
    char* wsb = (char*)d_ws;

    // ws layout (byte offsets), total 70,852,608 B = 67.6 MB.
    float*  emb_i = (float*)(wsb);                    // 9216 f32
    float*  emb_t = (float*)(wsb + 36864);            // 9216 f32
    bf16_t* wreg  = (bf16_t*)(wsb + 73728);           // 37.75 MB (weights, reused per stage)
    float*  part  = (float*)(wsb + 73728);            // adaln partials overlay
    float*  part_o = (float*)(wsb + 73728);           // attn partial O overlay (37.7 MB)
    bf16_t* n1    = (bf16_t*)(wsb + 37822464);        // 1536x1536 bf16 (LN1, later LN2)
    float*  part_ml = (float*)(wsb + 37822464);       // attn (m,l) overlay (n1 dead there)
    bf16_t* qkvb  = (bf16_t*)(wsb + 42541056);        // 1536x4608 bf16
    bf16_t* obuf  = qkvb;                             // alias (qkvb dead after epi/v_tr)
    bf16_t* ffb   = qkvb + 2359296;                   // 1536x6144 bf16 (bytes 47259648..66134016)
    bf16_t* qb    = (bf16_t*)(wsb + 56696832);        // 12x1536x128 bf16
    bf16_t* kb    = (bf16_t*)(wsb + 61415424);
    bf16_t* vt    = (bf16_t*)(wsb + 66134016);
    // K-split partial overlays (bf16 [z][1536][1536], 4,718,592 B each).
    // INVARIANT: MLP2 partial slots must NOT overlap ffb (47259648..66134016).
    bf16_t* pout = (bf16_t*)(wsb + 47259648);  // out-proj z=0,1 (ffb head; dead until MLP1)
    bf16_t* pm2  = (bf16_t*)(wsb + 37822464);  // MLP2 z=0,1 (n1+obuf; ends at ffb start)
    bf16_t* pm2b = (bf16_t*)(wsb + 66134016);  // MLP2 z=2 (vt; starts at ffb end)

    // 1. adaLN (K-split + reduce)
    adaln_p<<<dim3(72, 8), 256, 0, stream>>>(temb, adaln_img_w, adaln_txt_w, part);
    adaln_r<<<72, 256, 0, stream>>>(part, adaln_img_b, adaln_txt_b, emb_i, emb_t);
    // 2. LN1 + modulate -> bf16
    ln_mod<<<S_TOT, 256, 0, stream>>>(encoder, hidden, emb_t, emb_i, 0, 1, n1);
    // 3. QKV (864 blocks, gemmU)
    conv_wt<1536, 4608><<<dim3(72, 24, 2), 256, 0, stream>>>(qkv_txt_w, qkv_img_w, wreg);
    gemmU<0, bf16_t><<<dim3(72, 12), 256, 0, stream>>>(
        n1, D_MODEL, wreg, 1536, 4608 * 1536, qkv_txt_b, qkv_img_b, qkvb, 4608, 1536);
    // 4. RMS + RoPE -> bf16 q,k ; V transpose
    qkv_epi<<<dim3(12, 1536), 128, 0, stream>>>(qkvb, rope, qn_img, kn_img, qn_txt, kn_txt, qb, kb);
    v_tr<<<dim3(12, 24), 256, 0, stream>>>(qkvb, vt);
    // 5. attention (KV-split, single-buffer LDS) + reduce -> o bf16
    attn_k<<<dim3(12, 24, KVSPLIT), 256, 0, stream>>>(qb, kb, vt, part_o, part_ml);
    attn_red<<<HQB, 256, 0, stream>>>(part_o, part_ml, obuf);
    // 6. out-proj: K-split x2 (576 blocks, gemmU) + fused reduce epilogue
    conv_wt<1536, 1536><<<dim3(24, 24, 2), 256, 0, stream>>>(out_txt_w, out_img_w, wreg);
    gemmU<3, bf16_t><<<dim3(24, 12, 2), 256, 0, stream>>>(
        obuf, D_MODEL, wreg, 1536, 1536 * 1536, nullptr, nullptr, pout, D_MODEL, 768);
    gemm_red<2><<<S_TOT, 256, 0, stream>>>(
        pout, nullptr, out_txt_b, out_img_b,
        emb_t + 2 * D_MODEL, emb_i + 2 * D_MODEL, encoder, hidden, dout);
    // 7. LN2 + modulate -> bf16
    ln_mod<<<S_TOT, 256, 0, stream>>>(dout, dout + (size_t)S_TXT * D_MODEL, emb_t, emb_i, 3, 4, n1);
    // 8. MLP up + gelu -> bf16 ff (576 blocks, gemmV 128x128)
    conv_wt<1536, 6144><<<dim3(96, 24, 2), 256, 0, stream>>>(mlp_txt_w1, mlp_img_w1, wreg);
    gemmV<1><<<dim3(48, 12), 256, 0, stream>>>(
        n1, D_MODEL, wreg, 1536, 6144 * 1536, mlp_txt_b1, mlp_img_b1,
        ffb, nullptr, FF_DIM, 1536);
    // 9. MLP down: K-split x3 (432 blocks, gemmV) + fused reduce (in-place)
    conv_wt<6144, 1536><<<dim3(24, 96, 2), 256, 0, stream>>>(mlp_txt_w2, mlp_img_w2, wreg);
    gemmV<3><<<dim3(12, 12, 3), 256, 0, stream>>>(
        ffb, FF_DIM, wreg, 6144, 1536 * 6144, nullptr, nullptr,
        pm2, pm2b, D_MODEL, 2048);
    gemm_red<3><<<S_TOT, 256, 0, stream>>>(
        pm2, pm2b, mlp_txt_b2, mlp_img_b2,
        emb_t + 5 * D_MODEL, emb_i + 5 * D_MODEL,
        dout, dout + (size_t)S_TXT * D_MODEL, dout);
    (void)in_sizes; (void)n_in; (void)out_size; (void)ws_size;
}

// Round 14
// 331.786 us; speedup vs baseline: 1.0755x; 1.0351x over previous
//
#include <hip/hip_runtime.h>
#include <hip/hip_bf16.h>

typedef __bf16 bf16_t;
typedef __attribute__((ext_vector_type(4))) float f32x4;
typedef __attribute__((ext_vector_type(8))) bf16_t bf16x8;
typedef __attribute__((ext_vector_type(4))) bf16_t bf16x4;
typedef __attribute__((ext_vector_type(2))) bf16_t bf16x2;

#define D_MODEL 1536
#define NH 12
#define DHD 128
#define S_TXT 512
#define S_TOT 1536
#define FF_DIM 6144
#define KVSPLIT 4
#define HQB 288   // 12 heads * 24 q-blocks

// async global->LDS, 16 B per lane. LDS dest is wave-uniform base (+lane*16 by HW).
__device__ inline void gload16(const void* g, void* l) {
    __builtin_amdgcn_global_load_lds((const __attribute__((address_space(1))) unsigned int*)g,
                                     (__attribute__((address_space(3))) unsigned int*)l, 16, 0, 0);
}

// ---------------------------------------------------------------------------
// adaLN stage 1: partial dot products, K split 8 ways. grid (72,8) block 256.
// ---------------------------------------------------------------------------
__global__ __launch_bounds__(256)
void adaln_p(const float* __restrict__ temb,
             const float* __restrict__ w_img, const float* __restrict__ w_txt,
             float* __restrict__ part) {
    __shared__ float t[192];
    int tid = threadIdx.x;
    int k0 = blockIdx.y * 192;
    if (tid < 192) {
        float x = temb[k0 + tid];
        t[tid] = x / (1.0f + __expf(-x));
    }
    __syncthreads();
    int n_g = blockIdx.x * 256 + tid;
    bool img = n_g < 9216;
    const float* W = img ? w_img : w_txt;
    int n = img ? n_g : n_g - 9216;
    float acc = 0.f;
    for (int kk = 0; kk < 192; kk += 4) {
        acc += t[kk]     * W[(size_t)(k0 + kk) * 9216 + n];
        acc += t[kk + 1] * W[(size_t)(k0 + kk + 1) * 9216 + n];
        acc += t[kk + 2] * W[(size_t)(k0 + kk + 2) * 9216 + n];
        acc += t[kk + 3] * W[(size_t)(k0 + kk + 3) * 9216 + n];
    }
    part[(size_t)blockIdx.y * 18432 + n_g] = acc;
}

// adaLN stage 2: reduce + bias. grid 72 x 256.
__global__ __launch_bounds__(256)
void adaln_r(const float* __restrict__ part,
             const float* __restrict__ b_img, const float* __restrict__ b_txt,
             float* __restrict__ emb_img, float* __restrict__ emb_txt) {
    int n_g = blockIdx.x * 256 + threadIdx.x;
    float a = 0.f;
#pragma unroll
    for (int kc = 0; kc < 8; ++kc) a += part[(size_t)kc * 18432 + n_g];
    if (n_g < 9216) emb_img[n_g] = a + b_img[n_g];
    else            emb_txt[n_g - 9216] = a + b_txt[n_g - 9216];
}

// ---------------------------------------------------------------------------
// LayerNorm + modulate -> bf16. Rows 0..511 txt, 512..1535 img.
// ---------------------------------------------------------------------------
__global__ __launch_bounds__(256)
void ln_mod(const float* __restrict__ src_txt, const float* __restrict__ src_img,
            const float* __restrict__ emb_t, const float* __restrict__ emb_i,
            int sh_c, int sc_c, bf16_t* __restrict__ out) {
    int row = blockIdx.x;
    bool txt = row < S_TXT;
    const float* src = txt ? src_txt + (size_t)row * D_MODEL
                           : src_img + (size_t)(row - S_TXT) * D_MODEL;
    const float* emb = txt ? emb_t : emb_i;
    int tid = threadIdx.x;
    float2 v[3];
    float s = 0.f, sq = 0.f;
#pragma unroll
    for (int i = 0; i < 3; ++i) {
        v[i] = *(const float2*)(src + tid * 2 + 512 * i);
        s  += v[i].x + v[i].y;
        sq += v[i].x * v[i].x + v[i].y * v[i].y;
    }
#pragma unroll
    for (int off = 32; off > 0; off >>= 1) {
        s  += __shfl_down(s, off);
        sq += __shfl_down(sq, off);
    }
    __shared__ float red[8];
    int wave = tid >> 6, lane = tid & 63;
    if (lane == 0) { red[wave] = s; red[4 + wave] = sq; }
    __syncthreads();
    float ts = red[0] + red[1] + red[2] + red[3];
    float tq = red[4] + red[5] + red[6] + red[7];
    float mean = ts * (1.0f / D_MODEL);
    float var  = tq * (1.0f / D_MODEL) - mean * mean;
    float rstd = rsqrtf(var + 1e-6f);
    bf16_t* op = out + (size_t)row * D_MODEL;
#pragma unroll
    for (int i = 0; i < 3; ++i) {
        int c0 = tid * 2 + 512 * i;
        bf16x2 r;
        r[0] = (bf16_t)((v[i].x - mean) * rstd * (1.0f + emb[sc_c * D_MODEL + c0])     + emb[sh_c * D_MODEL + c0]);
        r[1] = (bf16_t)((v[i].y - mean) * rstd * (1.0f + emb[sc_c * D_MODEL + c0 + 1]) + emb[sh_c * D_MODEL + c0 + 1]);
        *(bf16x2*)(op + c0) = r;
    }
}

// ---------------------------------------------------------------------------
// Weight convert+transpose: W f32 [K][N] -> Wt bf16 [N][K]. grid (N/64,K/64,2).
// ---------------------------------------------------------------------------
template <int K, int N>
__global__ __launch_bounds__(256)
void conv_wt(const float* __restrict__ w_t, const float* __restrict__ w_i,
             bf16_t* __restrict__ dst) {
    __shared__ float tile[64][65];
    const float* src = blockIdx.z ? w_i : w_t;
    bf16_t* d = dst + (size_t)blockIdx.z * N * K;
    int bn = blockIdx.x * 64, bk = blockIdx.y * 64;
    int tid = threadIdx.x;
#pragma unroll
    for (int j = 0; j < 4; ++j) {
        int k = (tid >> 4) + 16 * j, c4 = tid & 15;
        float4 v = *(const float4*)(src + (size_t)(bk + k) * N + bn + c4 * 4);
        tile[k][c4 * 4 + 0] = v.x;
        tile[k][c4 * 4 + 1] = v.y;
        tile[k][c4 * 4 + 2] = v.z;
        tile[k][c4 * 4 + 3] = v.w;
    }
    __syncthreads();
#pragma unroll
    for (int j = 0; j < 4; ++j) {
        int n = (tid >> 4) + 16 * j, k4 = tid & 15;
        bf16x4 o;
        o[0] = (bf16_t)tile[k4 * 4 + 0][n];
        o[1] = (bf16_t)tile[k4 * 4 + 1][n];
        o[2] = (bf16_t)tile[k4 * 4 + 2][n];
        o[3] = (bf16_t)tile[k4 * 4 + 3][n];
        *(bf16x4*)(d + (size_t)(bn + n) * K + bk + k4 * 4) = o;
    }
}

// ---------------------------------------------------------------------------
// gemmU (R10 version): 128x64 tile, BK=64, 4 waves, single-buffer 24 KB LDS.
// Used for QKV and out-proj. L2 supertile swizzle; 8-chunk XOR (2-way free).
// EPI: 0=bias(bf16) 3=raw partial (bf16, z-th partial at out + z*1536*ldo).
// ---------------------------------------------------------------------------
template <int EPI, typename OutT>
__global__ __launch_bounds__(256)
void gemmU(const bf16_t* __restrict__ A, int lda,
           const bf16_t* __restrict__ Wt, int ldw, int wimg_off,
           const float* __restrict__ bias_t, const float* __restrict__ bias_i,
           OutT* __restrict__ out, int ldo, int Ks) {
    __shared__ bf16_t As[128 * 64];
    __shared__ bf16_t Bs[64 * 64];
    const int tid = threadIdx.x;

    const int nbx = gridDim.x, nby = gridDim.y;
    const int nwg = nbx * nby;
    const int lb0 = blockIdx.y * nbx + blockIdx.x;
    int bmT, bnT;
    if (nby == 12 && (nbx & 3) == 0 && (nwg & 7) == 0) {
        const int CC = nbx >> 2;
        const int xcd = lb0 & 7, c = lb0 >> 3;
        bmT = (xcd & 1) * 6 + (c % 6);
        bnT = (xcd >> 1) * CC + (c / 6);
    } else {
        int lb = lb0;
        if ((nwg & 7) == 0) lb = (lb & 7) * (nwg >> 3) + (lb >> 3);
        bmT = lb / nbx; bnT = lb % nbx;
    }
    const int bm = bmT * 128, bn = bnT * 64;
    const int koff = blockIdx.z * Ks;

    const bool txt = bm < S_TXT;
    const bf16_t* W = txt ? Wt : Wt + wimg_off;
    const float* bias = txt ? bias_t : bias_i;
    const int wave = tid >> 6, lane = tid & 63;
    const int wr = (wave >> 1) * 64, wc = (wave & 1) * 32;
    const int lr = lane & 15, lg = lane >> 4;

    const int srow = wave * 8 + (lane >> 3);
    const int csrc = ((lane & 7) ^ ((lane >> 3) & 7)) * 8;
    const bf16_t* Ab = A + (size_t)(bm + srow) * lda + koff + csrc;
    const bf16_t* Wb = W + (size_t)(bn + srow) * ldw + koff + csrc;
    const int ldst = (wave * 8) * 64;

    f32x4 acc[4][2] = {};
    const int nt = Ks >> 6;

    for (int t = 0; t < nt; ++t) {
#pragma unroll
        for (int j = 0; j < 4; ++j)
            gload16(Ab + (size_t)j * 32 * lda + t * 64, &As[ldst + j * 2048]);
#pragma unroll
        for (int j = 0; j < 2; ++j)
            gload16(Wb + (size_t)j * 32 * ldw + t * 64, &Bs[ldst + j * 2048]);
        __syncthreads();
#pragma unroll
        for (int kk = 0; kk < 2; ++kk) {
            bf16x8 af[4], bfm[2];
#pragma unroll
            for (int m = 0; m < 4; ++m) {
                int rr = wr + m * 16 + lr;
                af[m] = *(const bf16x8*)&As[rr * 64 + (((kk * 4 + lg) ^ (lr & 7)) * 8)];
            }
#pragma unroll
            for (int n = 0; n < 2; ++n) {
                int rr = wc + n * 16 + lr;
                bfm[n] = *(const bf16x8*)&Bs[rr * 64 + (((kk * 4 + lg) ^ (lr & 7)) * 8)];
            }
#pragma unroll
            for (int m = 0; m < 4; ++m)
#pragma unroll
                for (int n = 0; n < 2; ++n)
                    acc[m][n] = __builtin_amdgcn_mfma_f32_16x16x32_bf16(af[m], bfm[n], acc[m][n], 0, 0, 0);
        }
        __syncthreads();
    }

    OutT* obase = out;
    if constexpr (EPI == 3) obase = out + (size_t)blockIdx.z * S_TOT * ldo;
#pragma unroll
    for (int m = 0; m < 4; ++m) {
#pragma unroll
        for (int r = 0; r < 4; ++r) {
            int grow = bm + wr + m * 16 + lg * 4 + r;
#pragma unroll
            for (int n = 0; n < 2; ++n) {
                int gcol = bn + wc + n * 16 + lr;
                float v = acc[m][n][r];
                if constexpr (EPI != 3) v += bias[gcol];
                obase[(size_t)grow * ldo + gcol] = (OutT)v;
            }
        }
    }
}

// ---------------------------------------------------------------------------
// gemmW: 128x128 tile, BK=64, 512 threads / 8 waves (4Mx2N, wave tile 32x64,
// acc[2][4]). Doubles resident waves/CU for grid-limited dispatches (576/432
// blocks) and halves per-thread staging (4 loads). Strength-reduced pointers
// + precomputed LDS frag offsets (VALU cut). Single-buffer 32 KB LDS, m97
// 2-barrier loop, supertile swizzle (nby==12 assumed).
// EPI: 1=bias+gelu(bf16) 3=raw partial (z<2 -> out+z*slot, z>=2 -> out_alt).
// ---------------------------------------------------------------------------
template <int EPI>
__global__ __launch_bounds__(512)
void gemmW(const bf16_t* __restrict__ A, int lda,
           const bf16_t* __restrict__ Wt, int ldw, int wimg_off,
           const float* __restrict__ bias_t, const float* __restrict__ bias_i,
           bf16_t* __restrict__ out, bf16_t* __restrict__ out_alt, int ldo, int Ks) {
    __shared__ bf16_t As[128 * 64];
    __shared__ bf16_t Bs[128 * 64];
    const int tid = threadIdx.x;

    const int nbx = gridDim.x;
    const int lb0 = blockIdx.y * nbx + blockIdx.x;
    const int CC = nbx >> 2;
    const int xcd = lb0 & 7, c = lb0 >> 3;
    const int bmT = (xcd & 1) * 6 + (c % 6);
    const int bnT = (xcd >> 1) * CC + (c / 6);
    const int bm = bmT * 128, bn = bnT * 128;
    const int koff = blockIdx.z * Ks;

    const bool txt = bm < S_TXT;
    const bf16_t* W = txt ? Wt : Wt + wimg_off;
    const float* bias = txt ? bias_t : bias_i;
    const int wid = tid >> 6, lane = tid & 63;
    const int wm = wid >> 1, wn = wid & 1;          // 4(M) x 2(N) wave grid
    const int lr = lane & 15, lg = lane >> 4;

    // staging: 8 waves x 8 rows each, 2 rounds for A (128 rows) and B (128).
    const int srow = wid * 8 + (lane >> 3);         // 0..63
    const int csrc = ((lane & 7) ^ ((lane >> 3) & 7)) * 8;
    const bf16_t* pA0 = A + (size_t)(bm + srow) * lda + koff + csrc;
    const bf16_t* pA1 = pA0 + (size_t)64 * lda;
    const bf16_t* pB0 = W + (size_t)(bn + srow) * ldw + koff + csrc;
    const bf16_t* pB1 = pB0 + (size_t)64 * ldw;
    const int ldst = (wid * 8) * 64;                // wave-uniform

    // precomputed LDS frag byte/elem offsets (loop-invariant)
    int offA[2][2], offB[4][2];
#pragma unroll
    for (int m = 0; m < 2; ++m)
#pragma unroll
        for (int kk = 0; kk < 2; ++kk)
            offA[m][kk] = (wm * 32 + m * 16 + lr) * 64 + (((kk * 4 + lg) ^ (lr & 7)) * 8);
#pragma unroll
    for (int n = 0; n < 4; ++n)
#pragma unroll
        for (int kk = 0; kk < 2; ++kk)
            offB[n][kk] = (wn * 64 + n * 16 + lr) * 64 + (((kk * 4 + lg) ^ (lr & 7)) * 8);

    f32x4 acc[2][4] = {};
    const int nt = Ks >> 6;

    for (int t = 0; t < nt; ++t) {
        gload16(pA0, &As[ldst]);
        gload16(pA1, &As[ldst + 64 * 64]);
        gload16(pB0, &Bs[ldst]);
        gload16(pB1, &Bs[ldst + 64 * 64]);
        pA0 += 64; pA1 += 64; pB0 += 64; pB1 += 64;
        __syncthreads();   // drains vmcnt -> tiles ready
#pragma unroll
        for (int kk = 0; kk < 2; ++kk) {
            bf16x8 af[2], bfm[4];
#pragma unroll
            for (int m = 0; m < 2; ++m) af[m] = *(const bf16x8*)&As[offA[m][kk]];
#pragma unroll
            for (int n = 0; n < 4; ++n) bfm[n] = *(const bf16x8*)&Bs[offB[n][kk]];
#pragma unroll
            for (int m = 0; m < 2; ++m)
#pragma unroll
                for (int n = 0; n < 4; ++n)
                    acc[m][n] = __builtin_amdgcn_mfma_f32_16x16x32_bf16(af[m], bfm[n], acc[m][n], 0, 0, 0);
        }
        __syncthreads();   // reads done before next stage overwrites
    }

    bf16_t* obase = out;
    if constexpr (EPI == 3)
        obase = (blockIdx.z < 2) ? out + (size_t)blockIdx.z * S_TOT * ldo
                                 : out_alt + (size_t)(blockIdx.z - 2) * S_TOT * ldo;
#pragma unroll
    for (int m = 0; m < 2; ++m) {
#pragma unroll
        for (int r = 0; r < 4; ++r) {
            int grow = bm + wm * 32 + m * 16 + lg * 4 + r;
#pragma unroll
            for (int n = 0; n < 4; ++n) {
                int gcol = bn + wn * 64 + n * 16 + lr;
                float v = acc[m][n][r];
                if constexpr (EPI == 1) {
                    float x = v + bias[gcol];
                    float th = tanhf(0.7978845608028654f * (x + 0.044715f * x * x * x));
                    v = 0.5f * x * (1.0f + th);
                }
                obase[(size_t)grow * ldo + gcol] = (bf16_t)v;
            }
        }
    }
}

// ---------------------------------------------------------------------------
// K-split reduce: out = resid + gate*(bias + sum_s partial_s). grid 1536 x 256.
// partials bf16: slots 0,1 at p; slots >=2 at p_alt.
// ---------------------------------------------------------------------------
template <int NS>
__global__ __launch_bounds__(256)
void gemm_red(const bf16_t* __restrict__ p, const bf16_t* __restrict__ p_alt,
              const float* __restrict__ bias_t, const float* __restrict__ bias_i,
              const float* __restrict__ gate_t, const float* __restrict__ gate_i,
              const float* __restrict__ resid_t, const float* __restrict__ resid_i,
              float* __restrict__ out) {
    int r = blockIdx.x;
    bool txt = r < S_TXT;
    const float* bias = txt ? bias_t : bias_i;
    const float* gate = txt ? gate_t : gate_i;
    const float* resid = txt ? resid_t + (size_t)r * D_MODEL
                             : resid_i + (size_t)(r - S_TXT) * D_MODEL;
    int tid = threadIdx.x;
#pragma unroll
    for (int i = 0; i < 3; ++i) {
        int c = tid * 2 + 512 * i;
        float v0 = 0.f, v1 = 0.f;
#pragma unroll
        for (int s = 0; s < NS; ++s) {
            const bf16_t* ps = (s < 2) ? p + (size_t)s * S_TOT * D_MODEL
                                       : p_alt + (size_t)(s - 2) * S_TOT * D_MODEL;
            bf16x2 t2 = *(const bf16x2*)&ps[(size_t)r * D_MODEL + c];
            v0 += (float)t2[0];
            v1 += (float)t2[1];
        }
        float2 o;
        o.x = resid[c]     + gate[c]     * (v0 + bias[c]);
        o.y = resid[c + 1] + gate[c + 1] * (v1 + bias[c + 1]);
        *(float2*)&out[(size_t)r * D_MODEL + c] = o;
    }
}

// ---------------------------------------------------------------------------
// QKV epilogue: RMS-norm(q,k) + RoPE + fold 1/sqrt(DH) into q; bf16 in/out.
// ---------------------------------------------------------------------------
__global__ __launch_bounds__(128)
void qkv_epi(const bf16_t* __restrict__ qkv, const float* __restrict__ rope,
             const float* __restrict__ qn_i, const float* __restrict__ kn_i,
             const float* __restrict__ qn_t, const float* __restrict__ kn_t,
             bf16_t* __restrict__ qb, bf16_t* __restrict__ kb) {
    int h = blockIdx.x, s = blockIdx.y, dh = threadIdx.x;
    bool txt = s < S_TXT;
    const float* qn = txt ? qn_t : qn_i;
    const float* kn = txt ? kn_t : kn_i;
    const bf16_t* base = qkv + (size_t)s * 4608 + h * DHD + dh;
    float q = (float)base[0];
    float k = (float)base[D_MODEL];
    float qs = q * q, ks = k * k;
#pragma unroll
    for (int off = 32; off > 0; off >>= 1) {
        qs += __shfl_down(qs, off);
        ks += __shfl_down(ks, off);
    }
    __shared__ float red[4];
    if ((threadIdx.x & 63) == 0) {
        red[(threadIdx.x >> 6) * 2]     = qs;
        red[(threadIdx.x >> 6) * 2 + 1] = ks;
    }
    __syncthreads();
    float qr = rsqrtf((red[0] + red[2]) * (1.0f / DHD) + 1e-6f);
    float kr = rsqrtf((red[1] + red[3]) * (1.0f / DHD) + 1e-6f);
    q = q * qr * qn[dh];
    k = k * kr * kn[dh];
    int i = dh & 1, d = dh >> 1;
    const float* rp = rope + ((size_t)s * 64 + d) * 4 + i * 2;
    float r0 = rp[0], r1 = rp[1];
    float qo = __shfl_xor(q, 1), ko = __shfl_xor(k, 1);
    float q0 = i ? qo : q, q1 = i ? q : qo;
    float k0 = i ? ko : k, k1 = i ? k : ko;
    float qq = r0 * q0 + r1 * q1;
    float kk = r0 * k0 + r1 * k1;
    size_t idx = ((size_t)h * S_TOT + s) * DHD + dh;
    qb[idx] = (bf16_t)(qq * 0.08838834764831845f);  // 1/sqrt(128)
    kb[idx] = (bf16_t)kk;
}

// ---------------------------------------------------------------------------
// V transpose: per-head vT[DH][S] bf16. grid (12, 24), block 256.
// ---------------------------------------------------------------------------
__global__ __launch_bounds__(256)
void v_tr(const bf16_t* __restrict__ qkv, bf16_t* __restrict__ vt) {
    __shared__ bf16_t tile[64][130];
    int h = blockIdx.x, sb = blockIdx.y * 64;
    int tid = threadIdx.x;
#pragma unroll
    for (int j = 0; j < 32; ++j) {
        int linear = tid + 256 * j;
        int sl = linear >> 7, dh = linear & 127;
        tile[sl][dh] = qkv[(size_t)(sb + sl) * 4608 + 2 * D_MODEL + h * DHD + dh];
    }
    __syncthreads();
#pragma unroll
    for (int j = 0; j < 32; ++j) {
        int linear = tid + 256 * j;
        int dh = linear >> 6, sl = linear & 63;
        vt[((size_t)h * DHD + dh) * S_TOT + sb + sl] = tile[sl][dh];
    }
}

// ---------------------------------------------------------------------------
// Flash attention, KV-split, SINGLE-buffer LDS K/V (40 KB -> 4 blocks/CU).
// grid (12,24,KVSPLIT), 4 waves x 16 q-rows. 2 barriers per KV-tile.
// ---------------------------------------------------------------------------
__global__ __launch_bounds__(256)
void attn_k(const bf16_t* __restrict__ qbuf, const bf16_t* __restrict__ kbuf,
            const bf16_t* __restrict__ vt,
            float* __restrict__ part_o, float* __restrict__ part_ml) {
    __shared__ bf16_t Ks[64 * 128];
    __shared__ bf16_t Vs[128 * 64];
    __shared__ bf16_t P[4][16 * 64];
    int h = blockIdx.x, qblk = blockIdx.y, z = blockIdx.z;
    int q0 = qblk * 64;
    int tid = threadIdx.x, wave = tid >> 6, lane = tid & 63;
    int lr = lane & 15, lg = lane >> 4;

    const bf16_t* Qp = qbuf + ((size_t)h * S_TOT + q0 + wave * 16 + lr) * DHD;
    bf16x8 qf[4];
#pragma unroll
    for (int kk = 0; kk < 4; ++kk) qf[kk] = *(const bf16x8*)(Qp + (kk * 4 + lg) * 8);

    const int sKr = wave * 4 + (lane >> 4);
    const int cK = lane & 15;
    const bf16_t* Kb = kbuf + ((size_t)h * S_TOT + sKr) * DHD + ((cK ^ (sKr & 7)) * 8);
    const int sVr = wave * 8 + (lane >> 3);
    const int cV = lane & 7;
    const bf16_t* Vb = vt + ((size_t)h * DHD + sVr) * S_TOT + ((cV ^ (sVr & 7)) * 8);
    const int ldsV = (wave * 8) * 64;

    f32x4 of[8] = {};
    float m[4] = {-1e30f, -1e30f, -1e30f, -1e30f};
    float l[4] = {};
    const int kv0 = z * (S_TOT / KVSPLIT);
    const int nt = (S_TOT / KVSPLIT) / 64;

    for (int t = 0; t < nt; ++t) {
        const int kb0 = kv0 + t * 64;
#pragma unroll
        for (int j = 0; j < 4; ++j) {
            gload16(Kb + (size_t)(kb0 + j * 16) * DHD, &Ks[(wave * 4) * 128 + j * 2048]);
            gload16(Vb + kb0 + (size_t)j * 32 * S_TOT, &Vs[ldsV + j * 2048]);
        }
        asm volatile("s_waitcnt vmcnt(0)" ::: "memory");
        __builtin_amdgcn_s_barrier();          // K/V tile ready
        f32x4 sf[4] = {};
        __builtin_amdgcn_s_setprio(1);
#pragma unroll
        for (int n = 0; n < 4; ++n) {
#pragma unroll
            for (int kk = 0; kk < 4; ++kk) {
                bf16x8 kf = *(const bf16x8*)&Ks[(n * 16 + lr) * 128 + (((kk * 4 + lg) ^ (lr & 7)) * 8)];
                sf[n] = __builtin_amdgcn_mfma_f32_16x16x32_bf16(qf[kk], kf, sf[n], 0, 0, 0);
            }
        }
        __builtin_amdgcn_s_setprio(0);
        float bm[4], alpha[4], rs[4];
#pragma unroll
        for (int r = 0; r < 4; ++r)
            bm[r] = fmaxf(fmaxf(sf[0][r], sf[1][r]), fmaxf(sf[2][r], sf[3][r]));
#pragma unroll
        for (int mask = 1; mask < 16; mask <<= 1)
#pragma unroll
            for (int r = 0; r < 4; ++r) bm[r] = fmaxf(bm[r], __shfl_xor(bm[r], mask));
#pragma unroll
        for (int r = 0; r < 4; ++r) {
            float mn = fmaxf(m[r], bm[r]);
            alpha[r] = __expf(m[r] - mn);
            m[r] = mn;
            rs[r] = 0.f;
        }
#pragma unroll
        for (int n = 0; n < 4; ++n)
#pragma unroll
            for (int r = 0; r < 4; ++r) {
                float p = __expf(sf[n][r] - m[r]);
                rs[r] += p;
                int row = lg * 4 + r, col = n * 16 + lr;
                P[wave][row * 64 + ((((col >> 3) ^ (row & 7)) << 3) | (col & 7))] = (bf16_t)p;
            }
#pragma unroll
        for (int mask = 1; mask < 16; mask <<= 1)
#pragma unroll
            for (int r = 0; r < 4; ++r) rs[r] += __shfl_xor(rs[r], mask);
#pragma unroll
        for (int r = 0; r < 4; ++r) l[r] = l[r] * alpha[r] + rs[r];
#pragma unroll
        for (int nf = 0; nf < 8; ++nf)
#pragma unroll
            for (int r = 0; r < 4; ++r) of[nf][r] *= alpha[r];
        __builtin_amdgcn_s_setprio(1);
#pragma unroll
        for (int kk2 = 0; kk2 < 2; ++kk2) {
            bf16x8 pf = *(const bf16x8*)&P[wave][lr * 64 + (((kk2 * 4 + lg) ^ (lr & 7)) * 8)];
#pragma unroll
            for (int nf = 0; nf < 8; ++nf) {
                bf16x8 vf = *(const bf16x8*)&Vs[(nf * 16 + lr) * 64 + (((kk2 * 4 + lg) ^ (lr & 7)) * 8)];
                of[nf] = __builtin_amdgcn_mfma_f32_16x16x32_bf16(pf, vf, of[nf], 0, 0, 0);
            }
        }
        __builtin_amdgcn_s_setprio(0);
        __builtin_amdgcn_s_barrier();          // all waves done reading K/V
    }
    int hqb = h * 24 + qblk;
    float* po = part_o + ((size_t)z * HQB + hqb) * 8192;
    int rb = wave * 16 + lg * 4;
#pragma unroll
    for (int r = 0; r < 4; ++r)
#pragma unroll
        for (int nf = 0; nf < 8; ++nf)
            po[(rb + r) * 128 + nf * 16 + lr] = of[nf][r];
    if (lr == 0) {
#pragma unroll
        for (int r = 0; r < 4; ++r) {
            size_t mi = (((size_t)z * HQB + hqb) * 64 + rb + r) * 2;
            part_ml[mi]     = m[r];
            part_ml[mi + 1] = l[r];
        }
    }
}

// ---------------------------------------------------------------------------
// KV-split reduce: combine KVSPLIT partials -> bf16 o (S, D). grid 288 x 256.
// ---------------------------------------------------------------------------
__global__ __launch_bounds__(256)
void attn_red(const float* __restrict__ part_o, const float* __restrict__ part_ml,
              bf16_t* __restrict__ o) {
    int hqb = blockIdx.x;
    int h = hqb / 24, q0 = (hqb % 24) * 64;
    __shared__ float wz[KVSPLIT][64];
    __shared__ float invL[64];
    int tid = threadIdx.x;
    if (tid < 64) {
        float mz[KVSPLIT], lz[KVSPLIT];
#pragma unroll
        for (int zz = 0; zz < KVSPLIT; ++zz) {
            size_t mi = (((size_t)zz * HQB + hqb) * 64 + tid) * 2;
            mz[zz] = part_ml[mi];
            lz[zz] = part_ml[mi + 1];
        }
        float M = mz[0];
#pragma unroll
        for (int zz = 1; zz < KVSPLIT; ++zz) M = fmaxf(M, mz[zz]);
        float L = 0.f;
#pragma unroll
        for (int zz = 0; zz < KVSPLIT; ++zz) {
            float w = __expf(mz[zz] - M);
            wz[zz][tid] = w;
            L += w * lz[zz];
        }
        invL[tid] = 1.0f / L;
    }
    __syncthreads();
#pragma unroll
    for (int i = 0; i < 8; ++i) {
        int e4 = tid + 256 * i;
        int row = e4 >> 5, c4 = e4 & 31;
        f32x4 acc = {};
#pragma unroll
        for (int zz = 0; zz < KVSPLIT; ++zz) {
            f32x4 v = *(const f32x4*)&part_o[((size_t)zz * HQB + hqb) * 8192 + row * 128 + c4 * 4];
            float w = wz[zz][row];
            acc[0] += v[0] * w; acc[1] += v[1] * w; acc[2] += v[2] * w; acc[3] += v[3] * w;
        }
        float il = invL[row];
        bf16x4 r;
        r[0] = (bf16_t)(acc[0] * il); r[1] = (bf16_t)(acc[1] * il);
        r[2] = (bf16_t)(acc[2] * il); r[3] = (bf16_t)(acc[3] * il);
        *(bf16x4*)&o[(size_t)(q0 + row) * D_MODEL + h * DHD + c4 * 4] = r;
    }
}

// ---------------------------------------------------------------------------
extern "C" void kernel_launch(void* const* d_in, const int* in_sizes, int n_in,
                              void* d_out, int out_size, void* d_ws, size_t ws_size,
                              hipStream_t stream) {
    const float* hidden  = (const float*)d_in[0];
    const float* encoder = (const float*)d_in[1];
    const float* temb    = (const float*)d_in[2];
    const float* rope    = (const float*)d_in[3];
    const float* adaln_img_w = (const float*)d_in[4];
    const float* adaln_img_b = (const float*)d_in[5];
    const float* adaln_txt_w = (const float*)d_in[6];
    const float* adaln_txt_b = (const float*)d_in[7];
    const float* qkv_img_w = (const float*)d_in[8];
    const float* qkv_img_b = (const float*)d_in[9];
    const float* qkv_txt_w = (const float*)d_in[10];
    const float* qkv_txt_b = (const float*)d_in[11];
    const float* qn_img = (const float*)d_in[12];
    const float* kn_img = (const float*)d_in[13];
    const float* qn_txt = (const float*)d_in[14];
    const float* kn_txt = (const float*)d_in[15];
    const float* out_img_w = (const float*)d_in[16];
    const float* out_img_b = (const float*)d_in[17];
    const float* out_txt_w = (const float*)d_in[18];
    const float* out_txt_b = (const float*)d_in[19];
    const float* mlp_img_w1 = (const float*)d_in[20];
    const float* mlp_img_b1 = (const float*)d_in[21];
    const float* mlp_img_w2 = (const float*)d_in[22];
    const float* mlp_img_b2 = (const float*)d_in[23];
    const float* mlp_txt_w1 = (const float*)d_in[24];
    const float* mlp_txt_b1 = (const float*)d_in[25];
    const float* mlp_txt_w2 = (const float*)d_in[26];
    const float* mlp_txt_b2 = (const float*)d_in[27];
    float* dout = (float*)d_out;
    char* wsb = (char*)d_ws;

    // ws layout (byte offsets), total 70,852,608 B = 67.6 MB.
    float*  emb_i = (float*)(wsb);                    // 9216 f32
    float*  emb_t = (float*)(wsb + 36864);            // 9216 f32
    bf16_t* wreg  = (bf16_t*)(wsb + 73728);           // 37.75 MB (weights, reused per stage)
    float*  part  = (float*)(wsb + 73728);            // adaln partials overlay
    float*  part_o = (float*)(wsb + 73728);           // attn partial O overlay (37.7 MB)
    bf16_t* n1    = (bf16_t*)(wsb + 37822464);        // 1536x1536 bf16 (LN1, later LN2)
    float*  part_ml = (float*)(wsb + 37822464);       // attn (m,l) overlay (n1 dead there)
    bf16_t* qkvb  = (bf16_t*)(wsb + 42541056);        // 1536x4608 bf16
    bf16_t* obuf  = qkvb;                             // alias (qkvb dead after epi/v_tr)
    bf16_t* ffb   = qkvb + 2359296;                   // 1536x6144 bf16 (bytes 47259648..66134016)
    bf16_t* qb    = (bf16_t*)(wsb + 56696832);        // 12x1536x128 bf16
    bf16_t* kb    = (bf16_t*)(wsb + 61415424);
    bf16_t* vt    = (bf16_t*)(wsb + 66134016);
    // K-split partial overlays (bf16 [z][1536][1536], 4,718,592 B each).
    // INVARIANT: MLP2 partial slots must NOT overlap ffb (47259648..66134016).
    bf16_t* pout = (bf16_t*)(wsb + 47259648);  // out-proj z=0,1 (ffb head; dead until MLP1)
    bf16_t* pm2  = (bf16_t*)(wsb + 37822464);  // MLP2 z=0,1 (n1+obuf; ends at ffb start)
    bf16_t* pm2b = (bf16_t*)(wsb + 66134016);  // MLP2 z=2 (vt; starts at ffb end)

    // 1. adaLN (K-split + reduce)
    adaln_p<<<dim3(72, 8), 256, 0, stream>>>(temb, adaln_img_w, adaln_txt_w, part);
    adaln_r<<<72, 256, 0, stream>>>(part, adaln_img_b, adaln_txt_b, emb_i, emb_t);
    // 2. LN1 + modulate -> bf16
    ln_mod<<<S_TOT, 256, 0, stream>>>(encoder, hidden, emb_t, emb_i, 0, 1, n1);
    // 3. QKV (864 blocks, gemmU)
    conv_wt<1536, 4608><<<dim3(72, 24, 2), 256, 0, stream>>>(qkv_txt_w, qkv_img_w, wreg);
    gemmU<0, bf16_t><<<dim3(72, 12), 256, 0, stream>>>(
        n1, D_MODEL, wreg, 1536, 4608 * 1536, qkv_txt_b, qkv_img_b, qkvb, 4608, 1536);
    // 4. RMS + RoPE -> bf16 q,k ; V transpose
    qkv_epi<<<dim3(12, 1536), 128, 0, stream>>>(qkvb, rope, qn_img, kn_img, qn_txt, kn_txt, qb, kb);
    v_tr<<<dim3(12, 24), 256, 0, stream>>>(qkvb, vt);
    // 5. attention (KV-split, single-buffer LDS) + reduce -> o bf16
    attn_k<<<dim3(12, 24, KVSPLIT), 256, 0, stream>>>(qb, kb, vt, part_o, part_ml);
    attn_red<<<HQB, 256, 0, stream>>>(part_o, part_ml, obuf);
    // 6. out-proj: K-split x2 (576 blocks, gemmU) + fused reduce epilogue
    conv_wt<1536, 1536><<<dim3(24, 24, 2), 256, 0, stream>>>(out_txt_w, out_img_w, wreg);
    gemmU<3, bf16_t><<<dim3(24, 12, 2), 256, 0, stream>>>(
        obuf, D_MODEL, wreg, 1536, 1536 * 1536, nullptr, nullptr, pout, D_MODEL, 768);
    gemm_red<2><<<S_TOT, 256, 0, stream>>>(
        pout, nullptr, out_txt_b, out_img_b,
        emb_t + 2 * D_MODEL, emb_i + 2 * D_MODEL, encoder, hidden, dout);
    // 7. LN2 + modulate -> bf16
    ln_mod<<<S_TOT, 256, 0, stream>>>(dout, dout + (size_t)S_TXT * D_MODEL, emb_t, emb_i, 3, 4, n1);
    // 8. MLP up + gelu -> bf16 ff (576 blocks, gemmW 128x128 8-wave)
    conv_wt<1536, 6144><<<dim3(96, 24, 2), 256, 0, stream>>>(mlp_txt_w1, mlp_img_w1, wreg);
    gemmW<1><<<dim3(48, 12), 512, 0, stream>>>(
        n1, D_MODEL, wreg, 1536, 6144 * 1536, mlp_txt_b1, mlp_img_b1,
        ffb, nullptr, FF_DIM, 1536);
    // 9. MLP down: K-split x3 (432 blocks, gemmW) + fused reduce (in-place)
    conv_wt<6144, 1536><<<dim3(24, 96, 2), 256, 0, stream>>>(mlp_txt_w2, mlp_img_w2, wreg);
    gemmW<3><<<dim3(12, 12, 3), 512, 0, stream>>>(
        ffb, FF_DIM, wreg, 6144, 1536 * 6144, nullptr, nullptr,
        pm2, pm2b, D_MODEL, 2048);
    gemm_red<3><<<S_TOT, 256, 0, stream>>>(
        pm2, pm2b, mlp_txt_b2, mlp_img_b2,
        emb_t + 5 * D_MODEL, emb_i + 5 * D_MODEL,
        dout, dout + (size_t)S_TXT * D_MODEL, dout);
    (void)in_sizes; (void)n_in; (void)out_size; (void)ws_size;
}

// Round 15
// 328.630 us; speedup vs baseline: 1.0859x; 1.0096x over previous
//
#include <hip/hip_runtime.h>
#include <hip/hip_bf16.h>

typedef __bf16 bf16_t;
typedef __attribute__((ext_vector_type(4))) float f32x4;
typedef __attribute__((ext_vector_type(8))) bf16_t bf16x8;
typedef __attribute__((ext_vector_type(4))) bf16_t bf16x4;
typedef __attribute__((ext_vector_type(2))) bf16_t bf16x2;

#define D_MODEL 1536
#define NH 12
#define DHD 128
#define S_TXT 512
#define S_TOT 1536
#define FF_DIM 6144
#define KVSPLIT 4
#define HQB 288   // 12 heads * 24 q-blocks

// async global->LDS, 16 B per lane. LDS dest is wave-uniform base (+lane*16 by HW).
__device__ inline void gload16(const void* g, void* l) {
    __builtin_amdgcn_global_load_lds((const __attribute__((address_space(1))) unsigned int*)g,
                                     (__attribute__((address_space(3))) unsigned int*)l, 16, 0, 0);
}

// ---------------------------------------------------------------------------
// adaLN stage 1: partial dot products, K split 8 ways. grid (72,8) block 256.
// ---------------------------------------------------------------------------
__global__ __launch_bounds__(256)
void adaln_p(const float* __restrict__ temb,
             const float* __restrict__ w_img, const float* __restrict__ w_txt,
             float* __restrict__ part) {
    __shared__ float t[192];
    int tid = threadIdx.x;
    int k0 = blockIdx.y * 192;
    if (tid < 192) {
        float x = temb[k0 + tid];
        t[tid] = x / (1.0f + __expf(-x));
    }
    __syncthreads();
    int n_g = blockIdx.x * 256 + tid;
    bool img = n_g < 9216;
    const float* W = img ? w_img : w_txt;
    int n = img ? n_g : n_g - 9216;
    float acc = 0.f;
    for (int kk = 0; kk < 192; kk += 4) {
        acc += t[kk]     * W[(size_t)(k0 + kk) * 9216 + n];
        acc += t[kk + 1] * W[(size_t)(k0 + kk + 1) * 9216 + n];
        acc += t[kk + 2] * W[(size_t)(k0 + kk + 2) * 9216 + n];
        acc += t[kk + 3] * W[(size_t)(k0 + kk + 3) * 9216 + n];
    }
    part[(size_t)blockIdx.y * 18432 + n_g] = acc;
}

// adaLN stage 2: reduce + bias. grid 72 x 256.
__global__ __launch_bounds__(256)
void adaln_r(const float* __restrict__ part,
             const float* __restrict__ b_img, const float* __restrict__ b_txt,
             float* __restrict__ emb_img, float* __restrict__ emb_txt) {
    int n_g = blockIdx.x * 256 + threadIdx.x;
    float a = 0.f;
#pragma unroll
    for (int kc = 0; kc < 8; ++kc) a += part[(size_t)kc * 18432 + n_g];
    if (n_g < 9216) emb_img[n_g] = a + b_img[n_g];
    else            emb_txt[n_g - 9216] = a + b_txt[n_g - 9216];
}

// ---------------------------------------------------------------------------
// LayerNorm + modulate -> bf16. Rows 0..511 txt, 512..1535 img.
// ---------------------------------------------------------------------------
__global__ __launch_bounds__(256)
void ln_mod(const float* __restrict__ src_txt, const float* __restrict__ src_img,
            const float* __restrict__ emb_t, const float* __restrict__ emb_i,
            int sh_c, int sc_c, bf16_t* __restrict__ out) {
    int row = blockIdx.x;
    bool txt = row < S_TXT;
    const float* src = txt ? src_txt + (size_t)row * D_MODEL
                           : src_img + (size_t)(row - S_TXT) * D_MODEL;
    const float* emb = txt ? emb_t : emb_i;
    int tid = threadIdx.x;
    float2 v[3];
    float s = 0.f, sq = 0.f;
#pragma unroll
    for (int i = 0; i < 3; ++i) {
        v[i] = *(const float2*)(src + tid * 2 + 512 * i);
        s  += v[i].x + v[i].y;
        sq += v[i].x * v[i].x + v[i].y * v[i].y;
    }
#pragma unroll
    for (int off = 32; off > 0; off >>= 1) {
        s  += __shfl_down(s, off);
        sq += __shfl_down(sq, off);
    }
    __shared__ float red[8];
    int wave = tid >> 6, lane = tid & 63;
    if (lane == 0) { red[wave] = s; red[4 + wave] = sq; }
    __syncthreads();
    float ts = red[0] + red[1] + red[2] + red[3];
    float tq = red[4] + red[5] + red[6] + red[7];
    float mean = ts * (1.0f / D_MODEL);
    float var  = tq * (1.0f / D_MODEL) - mean * mean;
    float rstd = rsqrtf(var + 1e-6f);
    bf16_t* op = out + (size_t)row * D_MODEL;
#pragma unroll
    for (int i = 0; i < 3; ++i) {
        int c0 = tid * 2 + 512 * i;
        bf16x2 r;
        r[0] = (bf16_t)((v[i].x - mean) * rstd * (1.0f + emb[sc_c * D_MODEL + c0])     + emb[sh_c * D_MODEL + c0]);
        r[1] = (bf16_t)((v[i].y - mean) * rstd * (1.0f + emb[sc_c * D_MODEL + c0 + 1]) + emb[sh_c * D_MODEL + c0 + 1]);
        *(bf16x2*)(op + c0) = r;
    }
}

// ---------------------------------------------------------------------------
// Weight convert+transpose: W f32 [K][N] -> Wt bf16 [N][K]. grid (N/64,K/64,2).
// ---------------------------------------------------------------------------
template <int K, int N>
__global__ __launch_bounds__(256)
void conv_wt(const float* __restrict__ w_t, const float* __restrict__ w_i,
             bf16_t* __restrict__ dst) {
    __shared__ float tile[64][65];
    const float* src = blockIdx.z ? w_i : w_t;
    bf16_t* d = dst + (size_t)blockIdx.z * N * K;
    int bn = blockIdx.x * 64, bk = blockIdx.y * 64;
    int tid = threadIdx.x;
#pragma unroll
    for (int j = 0; j < 4; ++j) {
        int k = (tid >> 4) + 16 * j, c4 = tid & 15;
        float4 v = *(const float4*)(src + (size_t)(bk + k) * N + bn + c4 * 4);
        tile[k][c4 * 4 + 0] = v.x;
        tile[k][c4 * 4 + 1] = v.y;
        tile[k][c4 * 4 + 2] = v.z;
        tile[k][c4 * 4 + 3] = v.w;
    }
    __syncthreads();
#pragma unroll
    for (int j = 0; j < 4; ++j) {
        int n = (tid >> 4) + 16 * j, k4 = tid & 15;
        bf16x4 o;
        o[0] = (bf16_t)tile[k4 * 4 + 0][n];
        o[1] = (bf16_t)tile[k4 * 4 + 1][n];
        o[2] = (bf16_t)tile[k4 * 4 + 2][n];
        o[3] = (bf16_t)tile[k4 * 4 + 3][n];
        *(bf16x4*)(d + (size_t)(bn + n) * K + bk + k4 * 4) = o;
    }
}

// ---------------------------------------------------------------------------
// gemmW: 128x128 tile, BK=64, 512 threads / 8 waves (4Mx2N, wave tile 32x64,
// acc[2][4]). High waves/CU + halved per-thread staging + strength-reduced
// pointers and precomputed LDS frag offsets. Single-buffer 32 KB LDS, m97
// 2-barrier loop, supertile swizzle (nby==12 assumed; bijective for nbx%4==0).
// EPI: 0=bias(bf16) 1=bias+gelu(bf16) 3=raw partial (z<2 -> out, z>=2 -> out_alt).
// ---------------------------------------------------------------------------
template <int EPI>
__global__ __launch_bounds__(512)
void gemmW(const bf16_t* __restrict__ A, int lda,
           const bf16_t* __restrict__ Wt, int ldw, int wimg_off,
           const float* __restrict__ bias_t, const float* __restrict__ bias_i,
           bf16_t* __restrict__ out, bf16_t* __restrict__ out_alt, int ldo, int Ks) {
    __shared__ bf16_t As[128 * 64];
    __shared__ bf16_t Bs[128 * 64];
    const int tid = threadIdx.x;

    const int nbx = gridDim.x;
    const int lb0 = blockIdx.y * nbx + blockIdx.x;
    const int CC = nbx >> 2;
    const int xcd = lb0 & 7, c = lb0 >> 3;
    const int bmT = (xcd & 1) * 6 + (c % 6);
    const int bnT = (xcd >> 1) * CC + (c / 6);
    const int bm = bmT * 128, bn = bnT * 128;
    const int koff = blockIdx.z * Ks;

    const bool txt = bm < S_TXT;
    const bf16_t* W = txt ? Wt : Wt + wimg_off;
    const float* bias = txt ? bias_t : bias_i;
    const int wid = tid >> 6, lane = tid & 63;
    const int wm = wid >> 1, wn = wid & 1;          // 4(M) x 2(N) wave grid
    const int lr = lane & 15, lg = lane >> 4;

    const int srow = wid * 8 + (lane >> 3);         // 0..63
    const int csrc = ((lane & 7) ^ ((lane >> 3) & 7)) * 8;
    const bf16_t* pA0 = A + (size_t)(bm + srow) * lda + koff + csrc;
    const bf16_t* pA1 = pA0 + (size_t)64 * lda;
    const bf16_t* pB0 = W + (size_t)(bn + srow) * ldw + koff + csrc;
    const bf16_t* pB1 = pB0 + (size_t)64 * ldw;
    const int ldst = (wid * 8) * 64;                // wave-uniform

    int offA[2][2], offB[4][2];
#pragma unroll
    for (int m = 0; m < 2; ++m)
#pragma unroll
        for (int kk = 0; kk < 2; ++kk)
            offA[m][kk] = (wm * 32 + m * 16 + lr) * 64 + (((kk * 4 + lg) ^ (lr & 7)) * 8);
#pragma unroll
    for (int n = 0; n < 4; ++n)
#pragma unroll
        for (int kk = 0; kk < 2; ++kk)
            offB[n][kk] = (wn * 64 + n * 16 + lr) * 64 + (((kk * 4 + lg) ^ (lr & 7)) * 8);

    f32x4 acc[2][4] = {};
    const int nt = Ks >> 6;

    for (int t = 0; t < nt; ++t) {
        gload16(pA0, &As[ldst]);
        gload16(pA1, &As[ldst + 64 * 64]);
        gload16(pB0, &Bs[ldst]);
        gload16(pB1, &Bs[ldst + 64 * 64]);
        pA0 += 64; pA1 += 64; pB0 += 64; pB1 += 64;
        __syncthreads();   // drains vmcnt -> tiles ready
#pragma unroll
        for (int kk = 0; kk < 2; ++kk) {
            bf16x8 af[2], bfm[4];
#pragma unroll
            for (int m = 0; m < 2; ++m) af[m] = *(const bf16x8*)&As[offA[m][kk]];
#pragma unroll
            for (int n = 0; n < 4; ++n) bfm[n] = *(const bf16x8*)&Bs[offB[n][kk]];
#pragma unroll
            for (int m = 0; m < 2; ++m)
#pragma unroll
                for (int n = 0; n < 4; ++n)
                    acc[m][n] = __builtin_amdgcn_mfma_f32_16x16x32_bf16(af[m], bfm[n], acc[m][n], 0, 0, 0);
        }
        __syncthreads();   // reads done before next stage overwrites
    }

    bf16_t* obase = out;
    if constexpr (EPI == 3)
        obase = (blockIdx.z < 2) ? out + (size_t)blockIdx.z * S_TOT * ldo
                                 : out_alt + (size_t)(blockIdx.z - 2) * S_TOT * ldo;
#pragma unroll
    for (int m = 0; m < 2; ++m) {
#pragma unroll
        for (int r = 0; r < 4; ++r) {
            int grow = bm + wm * 32 + m * 16 + lg * 4 + r;
#pragma unroll
            for (int n = 0; n < 4; ++n) {
                int gcol = bn + wn * 64 + n * 16 + lr;
                float v = acc[m][n][r];
                if constexpr (EPI == 0) {
                    v += bias[gcol];
                } else if constexpr (EPI == 1) {
                    float x = v + bias[gcol];
                    float th = tanhf(0.7978845608028654f * (x + 0.044715f * x * x * x));
                    v = 0.5f * x * (1.0f + th);
                }
                obase[(size_t)grow * ldo + gcol] = (bf16_t)v;
            }
        }
    }
}

// ---------------------------------------------------------------------------
// K-split reduce: out = resid + gate*(bias + sum_s partial_s). grid 1536 x 256.
// partials bf16: slots 0,1 at p; slots >=2 at p_alt.
// ---------------------------------------------------------------------------
template <int NS>
__global__ __launch_bounds__(256)
void gemm_red(const bf16_t* __restrict__ p, const bf16_t* __restrict__ p_alt,
              const float* __restrict__ bias_t, const float* __restrict__ bias_i,
              const float* __restrict__ gate_t, const float* __restrict__ gate_i,
              const float* __restrict__ resid_t, const float* __restrict__ resid_i,
              float* __restrict__ out) {
    int r = blockIdx.x;
    bool txt = r < S_TXT;
    const float* bias = txt ? bias_t : bias_i;
    const float* gate = txt ? gate_t : gate_i;
    const float* resid = txt ? resid_t + (size_t)r * D_MODEL
                             : resid_i + (size_t)(r - S_TXT) * D_MODEL;
    int tid = threadIdx.x;
#pragma unroll
    for (int i = 0; i < 3; ++i) {
        int c = tid * 2 + 512 * i;
        float v0 = 0.f, v1 = 0.f;
#pragma unroll
        for (int s = 0; s < NS; ++s) {
            const bf16_t* ps = (s < 2) ? p + (size_t)s * S_TOT * D_MODEL
                                       : p_alt + (size_t)(s - 2) * S_TOT * D_MODEL;
            bf16x2 t2 = *(const bf16x2*)&ps[(size_t)r * D_MODEL + c];
            v0 += (float)t2[0];
            v1 += (float)t2[1];
        }
        float2 o;
        o.x = resid[c]     + gate[c]     * (v0 + bias[c]);
        o.y = resid[c + 1] + gate[c + 1] * (v1 + bias[c + 1]);
        *(float2*)&out[(size_t)r * D_MODEL + c] = o;
    }
}

// ---------------------------------------------------------------------------
// QKV epilogue: RMS-norm(q,k) + RoPE + fold 1/sqrt(DH) into q; bf16 in/out.
// ---------------------------------------------------------------------------
__global__ __launch_bounds__(128)
void qkv_epi(const bf16_t* __restrict__ qkv, const float* __restrict__ rope,
             const float* __restrict__ qn_i, const float* __restrict__ kn_i,
             const float* __restrict__ qn_t, const float* __restrict__ kn_t,
             bf16_t* __restrict__ qb, bf16_t* __restrict__ kb) {
    int h = blockIdx.x, s = blockIdx.y, dh = threadIdx.x;
    bool txt = s < S_TXT;
    const float* qn = txt ? qn_t : qn_i;
    const float* kn = txt ? kn_t : kn_i;
    const bf16_t* base = qkv + (size_t)s * 4608 + h * DHD + dh;
    float q = (float)base[0];
    float k = (float)base[D_MODEL];
    float qs = q * q, ks = k * k;
#pragma unroll
    for (int off = 32; off > 0; off >>= 1) {
        qs += __shfl_down(qs, off);
        ks += __shfl_down(ks, off);
    }
    __shared__ float red[4];
    if ((threadIdx.x & 63) == 0) {
        red[(threadIdx.x >> 6) * 2]     = qs;
        red[(threadIdx.x >> 6) * 2 + 1] = ks;
    }
    __syncthreads();
    float qr = rsqrtf((red[0] + red[2]) * (1.0f / DHD) + 1e-6f);
    float kr = rsqrtf((red[1] + red[3]) * (1.0f / DHD) + 1e-6f);
    q = q * qr * qn[dh];
    k = k * kr * kn[dh];
    int i = dh & 1, d = dh >> 1;
    const float* rp = rope + ((size_t)s * 64 + d) * 4 + i * 2;
    float r0 = rp[0], r1 = rp[1];
    float qo = __shfl_xor(q, 1), ko = __shfl_xor(k, 1);
    float q0 = i ? qo : q, q1 = i ? q : qo;
    float k0 = i ? ko : k, k1 = i ? k : ko;
    float qq = r0 * q0 + r1 * q1;
    float kk = r0 * k0 + r1 * k1;
    size_t idx = ((size_t)h * S_TOT + s) * DHD + dh;
    qb[idx] = (bf16_t)(qq * 0.08838834764831845f);  // 1/sqrt(128)
    kb[idx] = (bf16_t)kk;
}

// ---------------------------------------------------------------------------
// V transpose: per-head vT[DH][S] bf16. grid (12, 24), block 256.
// ---------------------------------------------------------------------------
__global__ __launch_bounds__(256)
void v_tr(const bf16_t* __restrict__ qkv, bf16_t* __restrict__ vt) {
    __shared__ bf16_t tile[64][130];
    int h = blockIdx.x, sb = blockIdx.y * 64;
    int tid = threadIdx.x;
#pragma unroll
    for (int j = 0; j < 32; ++j) {
        int linear = tid + 256 * j;
        int sl = linear >> 7, dh = linear & 127;
        tile[sl][dh] = qkv[(size_t)(sb + sl) * 4608 + 2 * D_MODEL + h * DHD + dh];
    }
    __syncthreads();
#pragma unroll
    for (int j = 0; j < 32; ++j) {
        int linear = tid + 256 * j;
        int dh = linear >> 6, sl = linear & 63;
        vt[((size_t)h * DHD + dh) * S_TOT + sb + sl] = tile[sl][dh];
    }
}

// ---------------------------------------------------------------------------
// Flash attention, KV-split, SINGLE-buffer LDS K/V (40 KB -> 4 blocks/CU).
// grid (12,24,KVSPLIT), 4 waves x 16 q-rows. 2 barriers per KV-tile.
// ---------------------------------------------------------------------------
__global__ __launch_bounds__(256)
void attn_k(const bf16_t* __restrict__ qbuf, const bf16_t* __restrict__ kbuf,
            const bf16_t* __restrict__ vt,
            float* __restrict__ part_o, float* __restrict__ part_ml) {
    __shared__ bf16_t Ks[64 * 128];
    __shared__ bf16_t Vs[128 * 64];
    __shared__ bf16_t P[4][16 * 64];
    int h = blockIdx.x, qblk = blockIdx.y, z = blockIdx.z;
    int q0 = qblk * 64;
    int tid = threadIdx.x, wave = tid >> 6, lane = tid & 63;
    int lr = lane & 15, lg = lane >> 4;

    const bf16_t* Qp = qbuf + ((size_t)h * S_TOT + q0 + wave * 16 + lr) * DHD;
    bf16x8 qf[4];
#pragma unroll
    for (int kk = 0; kk < 4; ++kk) qf[kk] = *(const bf16x8*)(Qp + (kk * 4 + lg) * 8);

    const int sKr = wave * 4 + (lane >> 4);
    const int cK = lane & 15;
    const bf16_t* Kb = kbuf + ((size_t)h * S_TOT + sKr) * DHD + ((cK ^ (sKr & 7)) * 8);
    const int sVr = wave * 8 + (lane >> 3);
    const int cV = lane & 7;
    const bf16_t* Vb = vt + ((size_t)h * DHD + sVr) * S_TOT + ((cV ^ (sVr & 7)) * 8);
    const int ldsV = (wave * 8) * 64;

    f32x4 of[8] = {};
    float m[4] = {-1e30f, -1e30f, -1e30f, -1e30f};
    float l[4] = {};
    const int kv0 = z * (S_TOT / KVSPLIT);
    const int nt = (S_TOT / KVSPLIT) / 64;

    for (int t = 0; t < nt; ++t) {
        const int kb0 = kv0 + t * 64;
#pragma unroll
        for (int j = 0; j < 4; ++j) {
            gload16(Kb + (size_t)(kb0 + j * 16) * DHD, &Ks[(wave * 4) * 128 + j * 2048]);
            gload16(Vb + kb0 + (size_t)j * 32 * S_TOT, &Vs[ldsV + j * 2048]);
        }
        asm volatile("s_waitcnt vmcnt(0)" ::: "memory");
        __builtin_amdgcn_s_barrier();          // K/V tile ready
        f32x4 sf[4] = {};
        __builtin_amdgcn_s_setprio(1);
#pragma unroll
        for (int n = 0; n < 4; ++n) {
#pragma unroll
            for (int kk = 0; kk < 4; ++kk) {
                bf16x8 kf = *(const bf16x8*)&Ks[(n * 16 + lr) * 128 + (((kk * 4 + lg) ^ (lr & 7)) * 8)];
                sf[n] = __builtin_amdgcn_mfma_f32_16x16x32_bf16(qf[kk], kf, sf[n], 0, 0, 0);
            }
        }
        __builtin_amdgcn_s_setprio(0);
        float bm[4], alpha[4], rs[4];
#pragma unroll
        for (int r = 0; r < 4; ++r)
            bm[r] = fmaxf(fmaxf(sf[0][r], sf[1][r]), fmaxf(sf[2][r], sf[3][r]));
#pragma unroll
        for (int mask = 1; mask < 16; mask <<= 1)
#pragma unroll
            for (int r = 0; r < 4; ++r) bm[r] = fmaxf(bm[r], __shfl_xor(bm[r], mask));
#pragma unroll
        for (int r = 0; r < 4; ++r) {
            float mn = fmaxf(m[r], bm[r]);
            alpha[r] = __expf(m[r] - mn);
            m[r] = mn;
            rs[r] = 0.f;
        }
#pragma unroll
        for (int n = 0; n < 4; ++n)
#pragma unroll
            for (int r = 0; r < 4; ++r) {
                float p = __expf(sf[n][r] - m[r]);
                rs[r] += p;
                int row = lg * 4 + r, col = n * 16 + lr;
                P[wave][row * 64 + ((((col >> 3) ^ (row & 7)) << 3) | (col & 7))] = (bf16_t)p;
            }
#pragma unroll
        for (int mask = 1; mask < 16; mask <<= 1)
#pragma unroll
            for (int r = 0; r < 4; ++r) rs[r] += __shfl_xor(rs[r], mask);
#pragma unroll
        for (int r = 0; r < 4; ++r) l[r] = l[r] * alpha[r] + rs[r];
#pragma unroll
        for (int nf = 0; nf < 8; ++nf)
#pragma unroll
            for (int r = 0; r < 4; ++r) of[nf][r] *= alpha[r];
        __builtin_amdgcn_s_setprio(1);
#pragma unroll
        for (int kk2 = 0; kk2 < 2; ++kk2) {
            bf16x8 pf = *(const bf16x8*)&P[wave][lr * 64 + (((kk2 * 4 + lg) ^ (lr & 7)) * 8)];
#pragma unroll
            for (int nf = 0; nf < 8; ++nf) {
                bf16x8 vf = *(const bf16x8*)&Vs[(nf * 16 + lr) * 64 + (((kk2 * 4 + lg) ^ (lr & 7)) * 8)];
                of[nf] = __builtin_amdgcn_mfma_f32_16x16x32_bf16(pf, vf, of[nf], 0, 0, 0);
            }
        }
        __builtin_amdgcn_s_setprio(0);
        __builtin_amdgcn_s_barrier();          // all waves done reading K/V
    }
    int hqb = h * 24 + qblk;
    float* po = part_o + ((size_t)z * HQB + hqb) * 8192;
    int rb = wave * 16 + lg * 4;
#pragma unroll
    for (int r = 0; r < 4; ++r)
#pragma unroll
        for (int nf = 0; nf < 8; ++nf)
            po[(rb + r) * 128 + nf * 16 + lr] = of[nf][r];
    if (lr == 0) {
#pragma unroll
        for (int r = 0; r < 4; ++r) {
            size_t mi = (((size_t)z * HQB + hqb) * 64 + rb + r) * 2;
            part_ml[mi]     = m[r];
            part_ml[mi + 1] = l[r];
        }
    }
}

// ---------------------------------------------------------------------------
// KV-split reduce: combine KVSPLIT partials -> bf16 o (S, D). grid 288 x 256.
// ---------------------------------------------------------------------------
__global__ __launch_bounds__(256)
void attn_red(const float* __restrict__ part_o, const float* __restrict__ part_ml,
              bf16_t* __restrict__ o) {
    int hqb = blockIdx.x;
    int h = hqb / 24, q0 = (hqb % 24) * 64;
    __shared__ float wz[KVSPLIT][64];
    __shared__ float invL[64];
    int tid = threadIdx.x;
    if (tid < 64) {
        float mz[KVSPLIT], lz[KVSPLIT];
#pragma unroll
        for (int zz = 0; zz < KVSPLIT; ++zz) {
            size_t mi = (((size_t)zz * HQB + hqb) * 64 + tid) * 2;
            mz[zz] = part_ml[mi];
            lz[zz] = part_ml[mi + 1];
        }
        float M = mz[0];
#pragma unroll
        for (int zz = 1; zz < KVSPLIT; ++zz) M = fmaxf(M, mz[zz]);
        float L = 0.f;
#pragma unroll
        for (int zz = 0; zz < KVSPLIT; ++zz) {
            float w = __expf(mz[zz] - M);
            wz[zz][tid] = w;
            L += w * lz[zz];
        }
        invL[tid] = 1.0f / L;
    }
    __syncthreads();
#pragma unroll
    for (int i = 0; i < 8; ++i) {
        int e4 = tid + 256 * i;
        int row = e4 >> 5, c4 = e4 & 31;
        f32x4 acc = {};
#pragma unroll
        for (int zz = 0; zz < KVSPLIT; ++zz) {
            f32x4 v = *(const f32x4*)&part_o[((size_t)zz * HQB + hqb) * 8192 + row * 128 + c4 * 4];
            float w = wz[zz][row];
            acc[0] += v[0] * w; acc[1] += v[1] * w; acc[2] += v[2] * w; acc[3] += v[3] * w;
        }
        float il = invL[row];
        bf16x4 r;
        r[0] = (bf16_t)(acc[0] * il); r[1] = (bf16_t)(acc[1] * il);
        r[2] = (bf16_t)(acc[2] * il); r[3] = (bf16_t)(acc[3] * il);
        *(bf16x4*)&o[(size_t)(q0 + row) * D_MODEL + h * DHD + c4 * 4] = r;
    }
}

// ---------------------------------------------------------------------------
extern "C" void kernel_launch(void* const* d_in, const int* in_sizes, int n_in,
                              void* d_out, int out_size, void* d_ws, size_t ws_size,
                              hipStream_t stream) {
    const float* hidden  = (const float*)d_in[0];
    const float* encoder = (const float*)d_in[1];
    const float* temb    = (const float*)d_in[2];
    const float* rope    = (const float*)d_in[3];
    const float* adaln_img_w = (const float*)d_in[4];
    const float* adaln_img_b = (const float*)d_in[5];
    const float* adaln_txt_w = (const float*)d_in[6];
    const float* adaln_txt_b = (const float*)d_in[7];
    const float* qkv_img_w = (const float*)d_in[8];
    const float* qkv_img_b = (const float*)d_in[9];
    const float* qkv_txt_w = (const float*)d_in[10];
    const float* qkv_txt_b = (const float*)d_in[11];
    const float* qn_img = (const float*)d_in[12];
    const float* kn_img = (const float*)d_in[13];
    const float* qn_txt = (const float*)d_in[14];
    const float* kn_txt = (const float*)d_in[15];
    const float* out_img_w = (const float*)d_in[16];
    const float* out_img_b = (const float*)d_in[17];
    const float* out_txt_w = (const float*)d_in[18];
    const float* out_txt_b = (const float*)d_in[19];
    const float* mlp_img_w1 = (const float*)d_in[20];
    const float* mlp_img_b1 = (const float*)d_in[21];
    const float* mlp_img_w2 = (const float*)d_in[22];
    const float* mlp_img_b2 = (const float*)d_in[23];
    const float* mlp_txt_w1 = (const float*)d_in[24];
    const float* mlp_txt_b1 = (const float*)d_in[25];
    const float* mlp_txt_w2 = (const float*)d_in[26];
    const float* mlp_txt_b2 = (const float*)d_in[27];
    float* dout = (float*)d_out;
    char* wsb = (char*)d_ws;

    // ws layout (byte offsets), total 70,852,608 B = 67.6 MB.
    float*  emb_i = (float*)(wsb);                    // 9216 f32
    float*  emb_t = (float*)(wsb + 36864);            // 9216 f32
    bf16_t* wreg  = (bf16_t*)(wsb + 73728);           // 37.75 MB (weights, reused per stage)
    float*  part  = (float*)(wsb + 73728);            // adaln partials overlay
    float*  part_o = (float*)(wsb + 73728);           // attn partial O overlay (37.7 MB)
    bf16_t* n1    = (bf16_t*)(wsb + 37822464);        // 1536x1536 bf16 (LN1, later LN2)
    float*  part_ml = (float*)(wsb + 37822464);       // attn (m,l) overlay (n1 dead there)
    bf16_t* qkvb  = (bf16_t*)(wsb + 42541056);        // 1536x4608 bf16
    bf16_t* obuf  = qkvb;                             // alias (qkvb dead after epi/v_tr)
    bf16_t* ffb   = qkvb + 2359296;                   // 1536x6144 bf16 (bytes 47259648..66134016)
    bf16_t* qb    = (bf16_t*)(wsb + 56696832);        // 12x1536x128 bf16
    bf16_t* kb    = (bf16_t*)(wsb + 61415424);
    bf16_t* vt    = (bf16_t*)(wsb + 66134016);
    // K-split partial overlays (bf16 [z][1536][1536], 4,718,592 B each).
    // INVARIANT: MLP2 partial slots must NOT overlap ffb (47259648..66134016).
    bf16_t* pout = (bf16_t*)(wsb + 47259648);  // out-proj z=0,1 (ffb head; dead until MLP1)
    bf16_t* pm2  = (bf16_t*)(wsb + 37822464);  // MLP2 z=0,1 (n1+obuf; ends at ffb start)
    bf16_t* pm2b = (bf16_t*)(wsb + 66134016);  // MLP2 z=2 (vt; starts at ffb end)

    // 1. adaLN (K-split + reduce)
    adaln_p<<<dim3(72, 8), 256, 0, stream>>>(temb, adaln_img_w, adaln_txt_w, part);
    adaln_r<<<72, 256, 0, stream>>>(part, adaln_img_b, adaln_txt_b, emb_i, emb_t);
    // 2. LN1 + modulate -> bf16
    ln_mod<<<S_TOT, 256, 0, stream>>>(encoder, hidden, emb_t, emb_i, 0, 1, n1);
    // 3. QKV (432 blocks, gemmW 8-wave)
    conv_wt<1536, 4608><<<dim3(72, 24, 2), 256, 0, stream>>>(qkv_txt_w, qkv_img_w, wreg);
    gemmW<0><<<dim3(36, 12), 512, 0, stream>>>(
        n1, D_MODEL, wreg, 1536, 4608 * 1536, qkv_txt_b, qkv_img_b,
        qkvb, nullptr, 4608, 1536);
    // 4. RMS + RoPE -> bf16 q,k ; V transpose
    qkv_epi<<<dim3(12, 1536), 128, 0, stream>>>(qkvb, rope, qn_img, kn_img, qn_txt, kn_txt, qb, kb);
    v_tr<<<dim3(12, 24), 256, 0, stream>>>(qkvb, vt);
    // 5. attention (KV-split, single-buffer LDS) + reduce -> o bf16
    attn_k<<<dim3(12, 24, KVSPLIT), 256, 0, stream>>>(qb, kb, vt, part_o, part_ml);
    attn_red<<<HQB, 256, 0, stream>>>(part_o, part_ml, obuf);
    // 6. out-proj: K-split x2 (288 blocks, gemmW) + fused reduce epilogue
    conv_wt<1536, 1536><<<dim3(24, 24, 2), 256, 0, stream>>>(out_txt_w, out_img_w, wreg);
    gemmW<3><<<dim3(12, 12, 2), 512, 0, stream>>>(
        obuf, D_MODEL, wreg, 1536, 1536 * 1536, nullptr, nullptr,
        pout, nullptr, D_MODEL, 768);
    gemm_red<2><<<S_TOT, 256, 0, stream>>>(
        pout, nullptr, out_txt_b, out_img_b,
        emb_t + 2 * D_MODEL, emb_i + 2 * D_MODEL, encoder, hidden, dout);
    // 7. LN2 + modulate -> bf16
    ln_mod<<<S_TOT, 256, 0, stream>>>(dout, dout + (size_t)S_TXT * D_MODEL, emb_t, emb_i, 3, 4, n1);
    // 8. MLP up + gelu -> bf16 ff (576 blocks, gemmW)
    conv_wt<1536, 6144><<<dim3(96, 24, 2), 256, 0, stream>>>(mlp_txt_w1, mlp_img_w1, wreg);
    gemmW<1><<<dim3(48, 12), 512, 0, stream>>>(
        n1, D_MODEL, wreg, 1536, 6144 * 1536, mlp_txt_b1, mlp_img_b1,
        ffb, nullptr, FF_DIM, 1536);
    // 9. MLP down: K-split x3 (432 blocks, gemmW) + fused reduce (in-place)
    conv_wt<6144, 1536><<<dim3(24, 96, 2), 256, 0, stream>>>(mlp_txt_w2, mlp_img_w2, wreg);
    gemmW<3><<<dim3(12, 12, 3), 512, 0, stream>>>(
        ffb, FF_DIM, wreg, 6144, 1536 * 6144, nullptr, nullptr,
        pm2, pm2b, D_MODEL, 2048);
    gemm_red<3><<<S_TOT, 256, 0, stream>>>(
        pm2, pm2b, mlp_txt_b2, mlp_img_b2,
        emb_t + 5 * D_MODEL, emb_i + 5 * D_MODEL,
        dout, dout + (size_t)S_TXT * D_MODEL, dout);
    (void)in_sizes; (void)n_in; (void)out_size; (void)ws_size;
}

// Round 16
// 318.582 us; speedup vs baseline: 1.1201x; 1.0315x over previous
//
#include <hip/hip_runtime.h>
#include <hip/hip_bf16.h>

typedef __bf16 bf16_t;
typedef __attribute__((ext_vector_type(4))) float f32x4;
typedef __attribute__((ext_vector_type(8))) bf16_t bf16x8;
typedef __attribute__((ext_vector_type(4))) bf16_t bf16x4;
typedef __attribute__((ext_vector_type(2))) bf16_t bf16x2;

#define D_MODEL 1536
#define NH 12
#define DHD 128
#define S_TXT 512
#define S_TOT 1536
#define FF_DIM 6144
#define KVSPLIT 4

// async global->LDS, 16 B per lane. LDS dest is wave-uniform base (+lane*16 by HW).
__device__ inline void gload16(const void* g, void* l) {
    __builtin_amdgcn_global_load_lds((const __attribute__((address_space(1))) unsigned int*)g,
                                     (__attribute__((address_space(3))) unsigned int*)l, 16, 0, 0);
}

// ---------------------------------------------------------------------------
// adaLN stage 1: partial dot products, K split 8 ways. grid (72,8) block 256.
// ---------------------------------------------------------------------------
__global__ __launch_bounds__(256)
void adaln_p(const float* __restrict__ temb,
             const float* __restrict__ w_img, const float* __restrict__ w_txt,
             float* __restrict__ part) {
    __shared__ float t[192];
    int tid = threadIdx.x;
    int k0 = blockIdx.y * 192;
    if (tid < 192) {
        float x = temb[k0 + tid];
        t[tid] = x / (1.0f + __expf(-x));
    }
    __syncthreads();
    int n_g = blockIdx.x * 256 + tid;
    bool img = n_g < 9216;
    const float* W = img ? w_img : w_txt;
    int n = img ? n_g : n_g - 9216;
    float acc = 0.f;
    for (int kk = 0; kk < 192; kk += 4) {
        acc += t[kk]     * W[(size_t)(k0 + kk) * 9216 + n];
        acc += t[kk + 1] * W[(size_t)(k0 + kk + 1) * 9216 + n];
        acc += t[kk + 2] * W[(size_t)(k0 + kk + 2) * 9216 + n];
        acc += t[kk + 3] * W[(size_t)(k0 + kk + 3) * 9216 + n];
    }
    part[(size_t)blockIdx.y * 18432 + n_g] = acc;
}

// adaLN stage 2: reduce + bias. grid 72 x 256.
__global__ __launch_bounds__(256)
void adaln_r(const float* __restrict__ part,
             const float* __restrict__ b_img, const float* __restrict__ b_txt,
             float* __restrict__ emb_img, float* __restrict__ emb_txt) {
    int n_g = blockIdx.x * 256 + threadIdx.x;
    float a = 0.f;
#pragma unroll
    for (int kc = 0; kc < 8; ++kc) a += part[(size_t)kc * 18432 + n_g];
    if (n_g < 9216) emb_img[n_g] = a + b_img[n_g];
    else            emb_txt[n_g - 9216] = a + b_txt[n_g - 9216];
}

// ---------------------------------------------------------------------------
// LayerNorm + modulate -> bf16 (LN1). Rows 0..511 txt, 512..1535 img.
// ---------------------------------------------------------------------------
__global__ __launch_bounds__(256)
void ln_mod(const float* __restrict__ src_txt, const float* __restrict__ src_img,
            const float* __restrict__ emb_t, const float* __restrict__ emb_i,
            int sh_c, int sc_c, bf16_t* __restrict__ out) {
    int row = blockIdx.x;
    bool txt = row < S_TXT;
    const float* src = txt ? src_txt + (size_t)row * D_MODEL
                           : src_img + (size_t)(row - S_TXT) * D_MODEL;
    const float* emb = txt ? emb_t : emb_i;
    int tid = threadIdx.x;
    float2 v[3];
    float s = 0.f, sq = 0.f;
#pragma unroll
    for (int i = 0; i < 3; ++i) {
        v[i] = *(const float2*)(src + tid * 2 + 512 * i);
        s  += v[i].x + v[i].y;
        sq += v[i].x * v[i].x + v[i].y * v[i].y;
    }
#pragma unroll
    for (int off = 32; off > 0; off >>= 1) {
        s  += __shfl_down(s, off);
        sq += __shfl_down(sq, off);
    }
    __shared__ float red[8];
    int wave = tid >> 6, lane = tid & 63;
    if (lane == 0) { red[wave] = s; red[4 + wave] = sq; }
    __syncthreads();
    float ts = red[0] + red[1] + red[2] + red[3];
    float tq = red[4] + red[5] + red[6] + red[7];
    float mean = ts * (1.0f / D_MODEL);
    float var  = tq * (1.0f / D_MODEL) - mean * mean;
    float rstd = rsqrtf(var + 1e-6f);
    bf16_t* op = out + (size_t)row * D_MODEL;
#pragma unroll
    for (int i = 0; i < 3; ++i) {
        int c0 = tid * 2 + 512 * i;
        bf16x2 r;
        r[0] = (bf16_t)((v[i].x - mean) * rstd * (1.0f + emb[sc_c * D_MODEL + c0])     + emb[sh_c * D_MODEL + c0]);
        r[1] = (bf16_t)((v[i].y - mean) * rstd * (1.0f + emb[sc_c * D_MODEL + c0 + 1]) + emb[sh_c * D_MODEL + c0 + 1]);
        *(bf16x2*)(op + c0) = r;
    }
}

// ---------------------------------------------------------------------------
// Weight convert+transpose: W f32 [K][N] -> Wt bf16 [N][K]. grid (N/64,K/64,2).
// ---------------------------------------------------------------------------
template <int K, int N>
__global__ __launch_bounds__(256)
void conv_wt(const float* __restrict__ w_t, const float* __restrict__ w_i,
             bf16_t* __restrict__ dst) {
    __shared__ float tile[64][65];
    const float* src = blockIdx.z ? w_i : w_t;
    bf16_t* d = dst + (size_t)blockIdx.z * N * K;
    int bn = blockIdx.x * 64, bk = blockIdx.y * 64;
    int tid = threadIdx.x;
#pragma unroll
    for (int j = 0; j < 4; ++j) {
        int k = (tid >> 4) + 16 * j, c4 = tid & 15;
        float4 v = *(const float4*)(src + (size_t)(bk + k) * N + bn + c4 * 4);
        tile[k][c4 * 4 + 0] = v.x;
        tile[k][c4 * 4 + 1] = v.y;
        tile[k][c4 * 4 + 2] = v.z;
        tile[k][c4 * 4 + 3] = v.w;
    }
    __syncthreads();
#pragma unroll
    for (int j = 0; j < 4; ++j) {
        int n = (tid >> 4) + 16 * j, k4 = tid & 15;
        bf16x4 o;
        o[0] = (bf16_t)tile[k4 * 4 + 0][n];
        o[1] = (bf16_t)tile[k4 * 4 + 1][n];
        o[2] = (bf16_t)tile[k4 * 4 + 2][n];
        o[3] = (bf16_t)tile[k4 * 4 + 3][n];
        *(bf16x4*)(d + (size_t)(bn + n) * K + bk + k4 * 4) = o;
    }
}

// ---------------------------------------------------------------------------
// gemmW: 128x128 tile, BK=64, 512 threads / 8 waves (4Mx2N, wave tile 32x64).
// Single-buffer 32 KB LDS, m97 2-barrier loop, supertile swizzle (nby==12).
// EPI: 0=bias(bf16) 1=bias+gelu(bf16) 3=raw partial (z<2 -> out, z>=2 -> out_alt).
// ---------------------------------------------------------------------------
template <int EPI>
__global__ __launch_bounds__(512)
void gemmW(const bf16_t* __restrict__ A, int lda,
           const bf16_t* __restrict__ Wt, int ldw, int wimg_off,
           const float* __restrict__ bias_t, const float* __restrict__ bias_i,
           bf16_t* __restrict__ out, bf16_t* __restrict__ out_alt, int ldo, int Ks) {
    __shared__ bf16_t As[128 * 64];
    __shared__ bf16_t Bs[128 * 64];
    const int tid = threadIdx.x;

    const int nbx = gridDim.x;
    const int lb0 = blockIdx.y * nbx + blockIdx.x;
    const int CC = nbx >> 2;
    const int xcd = lb0 & 7, c = lb0 >> 3;
    const int bmT = (xcd & 1) * 6 + (c % 6);
    const int bnT = (xcd >> 1) * CC + (c / 6);
    const int bm = bmT * 128, bn = bnT * 128;
    const int koff = blockIdx.z * Ks;

    const bool txt = bm < S_TXT;
    const bf16_t* W = txt ? Wt : Wt + wimg_off;
    const float* bias = txt ? bias_t : bias_i;
    const int wid = tid >> 6, lane = tid & 63;
    const int wm = wid >> 1, wn = wid & 1;          // 4(M) x 2(N) wave grid
    const int lr = lane & 15, lg = lane >> 4;

    const int srow = wid * 8 + (lane >> 3);         // 0..63
    const int csrc = ((lane & 7) ^ ((lane >> 3) & 7)) * 8;
    const bf16_t* pA0 = A + (size_t)(bm + srow) * lda + koff + csrc;
    const bf16_t* pA1 = pA0 + (size_t)64 * lda;
    const bf16_t* pB0 = W + (size_t)(bn + srow) * ldw + koff + csrc;
    const bf16_t* pB1 = pB0 + (size_t)64 * ldw;
    const int ldst = (wid * 8) * 64;                // wave-uniform

    int offA[2][2], offB[4][2];
#pragma unroll
    for (int m = 0; m < 2; ++m)
#pragma unroll
        for (int kk = 0; kk < 2; ++kk)
            offA[m][kk] = (wm * 32 + m * 16 + lr) * 64 + (((kk * 4 + lg) ^ (lr & 7)) * 8);
#pragma unroll
    for (int n = 0; n < 4; ++n)
#pragma unroll
        for (int kk = 0; kk < 2; ++kk)
            offB[n][kk] = (wn * 64 + n * 16 + lr) * 64 + (((kk * 4 + lg) ^ (lr & 7)) * 8);

    f32x4 acc[2][4] = {};
    const int nt = Ks >> 6;

    for (int t = 0; t < nt; ++t) {
        gload16(pA0, &As[ldst]);
        gload16(pA1, &As[ldst + 64 * 64]);
        gload16(pB0, &Bs[ldst]);
        gload16(pB1, &Bs[ldst + 64 * 64]);
        pA0 += 64; pA1 += 64; pB0 += 64; pB1 += 64;
        __syncthreads();   // drains vmcnt -> tiles ready
#pragma unroll
        for (int kk = 0; kk < 2; ++kk) {
            bf16x8 af[2], bfm[4];
#pragma unroll
            for (int m = 0; m < 2; ++m) af[m] = *(const bf16x8*)&As[offA[m][kk]];
#pragma unroll
            for (int n = 0; n < 4; ++n) bfm[n] = *(const bf16x8*)&Bs[offB[n][kk]];
#pragma unroll
            for (int m = 0; m < 2; ++m)
#pragma unroll
                for (int n = 0; n < 4; ++n)
                    acc[m][n] = __builtin_amdgcn_mfma_f32_16x16x32_bf16(af[m], bfm[n], acc[m][n], 0, 0, 0);
        }
        __syncthreads();   // reads done before next stage overwrites
    }

    bf16_t* obase = out;
    if constexpr (EPI == 3)
        obase = (blockIdx.z < 2) ? out + (size_t)blockIdx.z * S_TOT * ldo
                                 : out_alt + (size_t)(blockIdx.z - 2) * S_TOT * ldo;
#pragma unroll
    for (int m = 0; m < 2; ++m) {
#pragma unroll
        for (int r = 0; r < 4; ++r) {
            int grow = bm + wm * 32 + m * 16 + lg * 4 + r;
#pragma unroll
            for (int n = 0; n < 4; ++n) {
                int gcol = bn + wn * 64 + n * 16 + lr;
                float v = acc[m][n][r];
                if constexpr (EPI == 0) {
                    v += bias[gcol];
                } else if constexpr (EPI == 1) {
                    float x = v + bias[gcol];
                    float th = tanhf(0.7978845608028654f * (x + 0.044715f * x * x * x));
                    v = 0.5f * x * (1.0f + th);
                }
                obase[(size_t)grow * ldo + gcol] = (bf16_t)v;
            }
        }
    }
}

// ---------------------------------------------------------------------------
// K-split reduce: out = resid + gate*(bias + sum_s partial_s). grid 1536 x 256.
// ---------------------------------------------------------------------------
template <int NS>
__global__ __launch_bounds__(256)
void gemm_red(const bf16_t* __restrict__ p, const bf16_t* __restrict__ p_alt,
              const float* __restrict__ bias_t, const float* __restrict__ bias_i,
              const float* __restrict__ gate_t, const float* __restrict__ gate_i,
              const float* __restrict__ resid_t, const float* __restrict__ resid_i,
              float* __restrict__ out) {
    int r = blockIdx.x;
    bool txt = r < S_TXT;
    const float* bias = txt ? bias_t : bias_i;
    const float* gate = txt ? gate_t : gate_i;
    const float* resid = txt ? resid_t + (size_t)r * D_MODEL
                             : resid_i + (size_t)(r - S_TXT) * D_MODEL;
    int tid = threadIdx.x;
#pragma unroll
    for (int i = 0; i < 3; ++i) {
        int c = tid * 2 + 512 * i;
        float v0 = 0.f, v1 = 0.f;
#pragma unroll
        for (int s = 0; s < NS; ++s) {
            const bf16_t* ps = (s < 2) ? p + (size_t)s * S_TOT * D_MODEL
                                       : p_alt + (size_t)(s - 2) * S_TOT * D_MODEL;
            bf16x2 t2 = *(const bf16x2*)&ps[(size_t)r * D_MODEL + c];
            v0 += (float)t2[0];
            v1 += (float)t2[1];
        }
        float2 o;
        o.x = resid[c]     + gate[c]     * (v0 + bias[c]);
        o.y = resid[c + 1] + gate[c + 1] * (v1 + bias[c + 1]);
        *(float2*)&out[(size_t)r * D_MODEL + c] = o;
    }
}

// ---------------------------------------------------------------------------
// red_ln: fused out-proj K-split reduce + residual + LN2 + modulate.
// grid 1536 x 256. Writes dout (f32 residual stream) AND n1 (bf16 LN2 out).
// ---------------------------------------------------------------------------
__global__ __launch_bounds__(256)
void red_ln(const bf16_t* __restrict__ p,
            const float* __restrict__ bias_t, const float* __restrict__ bias_i,
            const float* __restrict__ gate_t, const float* __restrict__ gate_i,
            const float* __restrict__ resid_t, const float* __restrict__ resid_i,
            const float* __restrict__ emb_t, const float* __restrict__ emb_i,
            float* __restrict__ out, bf16_t* __restrict__ nout) {
    int r = blockIdx.x;
    bool txt = r < S_TXT;
    const float* bias = txt ? bias_t : bias_i;
    const float* gate = txt ? gate_t : gate_i;
    const float* resid = txt ? resid_t + (size_t)r * D_MODEL
                             : resid_i + (size_t)(r - S_TXT) * D_MODEL;
    const float* emb = txt ? emb_t : emb_i;
    int tid = threadIdx.x;
    float2 v[3];
    float s = 0.f, sq = 0.f;
#pragma unroll
    for (int i = 0; i < 3; ++i) {
        int c = tid * 2 + 512 * i;
        bf16x2 p0 = *(const bf16x2*)&p[(size_t)r * D_MODEL + c];
        bf16x2 p1 = *(const bf16x2*)&p[(size_t)(S_TOT + r) * D_MODEL + c];
        float2 o;
        o.x = resid[c]     + gate[c]     * ((float)p0[0] + (float)p1[0] + bias[c]);
        o.y = resid[c + 1] + gate[c + 1] * ((float)p0[1] + (float)p1[1] + bias[c + 1]);
        *(float2*)&out[(size_t)r * D_MODEL + c] = o;
        v[i] = o;
        s  += o.x + o.y;
        sq += o.x * o.x + o.y * o.y;
    }
#pragma unroll
    for (int off = 32; off > 0; off >>= 1) {
        s  += __shfl_down(s, off);
        sq += __shfl_down(sq, off);
    }
    __shared__ float red[8];
    int wave = tid >> 6, lane = tid & 63;
    if (lane == 0) { red[wave] = s; red[4 + wave] = sq; }
    __syncthreads();
    float ts = red[0] + red[1] + red[2] + red[3];
    float tq = red[4] + red[5] + red[6] + red[7];
    float mean = ts * (1.0f / D_MODEL);
    float var  = tq * (1.0f / D_MODEL) - mean * mean;
    float rstd = rsqrtf(var + 1e-6f);
    bf16_t* op = nout + (size_t)r * D_MODEL;
#pragma unroll
    for (int i = 0; i < 3; ++i) {
        int c0 = tid * 2 + 512 * i;
        bf16x2 o2;
        o2[0] = (bf16_t)((v[i].x - mean) * rstd * (1.0f + emb[4 * D_MODEL + c0])     + emb[3 * D_MODEL + c0]);
        o2[1] = (bf16_t)((v[i].y - mean) * rstd * (1.0f + emb[4 * D_MODEL + c0 + 1]) + emb[3 * D_MODEL + c0 + 1]);
        *(bf16x2*)(op + c0) = o2;
    }
}

// ---------------------------------------------------------------------------
// qkv_post: fused RMS+RoPE (q,k) + V transpose. grid (12,24), 256 threads.
// Part A: one wave per (h,s) row; lane l owns RoPE pair (2l, 2l+1) -> row
// sumsq via shfl_xor, rotation lane-local. Part B: v -> vT[DH][S] via LDS.
// ---------------------------------------------------------------------------
__global__ __launch_bounds__(256)
void qkv_post(const bf16_t* __restrict__ qkv, const float* __restrict__ rope,
              const float* __restrict__ qn_i, const float* __restrict__ kn_i,
              const float* __restrict__ qn_t, const float* __restrict__ kn_t,
              bf16_t* __restrict__ qb, bf16_t* __restrict__ kb,
              bf16_t* __restrict__ vt) {
    int h = blockIdx.x, sb = blockIdx.y * 64;
    int tid = threadIdx.x, wave = tid >> 6, lane = tid & 63;

    // ---- Part A: q,k RMS + RoPE, 4 rows per iter ----
#pragma unroll 4
    for (int it = 0; it < 16; ++it) {
        int s = sb + it * 4 + wave;
        bool txt = s < S_TXT;
        const float* qn = txt ? qn_t : qn_i;
        const float* kn = txt ? kn_t : kn_i;
        const bf16_t* base = qkv + (size_t)s * 4608 + h * DHD + lane * 2;
        bf16x2 qv = *(const bf16x2*)base;
        bf16x2 kv = *(const bf16x2*)(base + D_MODEL);
        float q0 = (float)qv[0], q1 = (float)qv[1];
        float k0 = (float)kv[0], k1 = (float)kv[1];
        float qs = q0 * q0 + q1 * q1, ks = k0 * k0 + k1 * k1;
#pragma unroll
        for (int mask = 32; mask > 0; mask >>= 1) {
            qs += __shfl_xor(qs, mask);
            ks += __shfl_xor(ks, mask);
        }
        float qr = rsqrtf(qs * (1.0f / DHD) + 1e-6f);
        float kr = rsqrtf(ks * (1.0f / DHD) + 1e-6f);
        float2 qn2 = *(const float2*)(qn + lane * 2);
        float2 kn2 = *(const float2*)(kn + lane * 2);
        q0 *= qr * qn2.x; q1 *= qr * qn2.y;
        k0 *= kr * kn2.x; k1 *= kr * kn2.y;
        float4 rp = *(const float4*)(rope + ((size_t)s * 64 + lane) * 4);
        float oq0 = rp.x * q0 + rp.y * q1, oq1 = rp.z * q0 + rp.w * q1;
        float ok0 = rp.x * k0 + rp.y * k1, ok1 = rp.z * k0 + rp.w * k1;
        size_t idx = ((size_t)h * S_TOT + s) * DHD + lane * 2;
        bf16x2 qo, ko;
        qo[0] = (bf16_t)(oq0 * 0.08838834764831845f);
        qo[1] = (bf16_t)(oq1 * 0.08838834764831845f);
        ko[0] = (bf16_t)ok0; ko[1] = (bf16_t)ok1;
        *(bf16x2*)&qb[idx] = qo;
        *(bf16x2*)&kb[idx] = ko;
    }

    // ---- Part B: V transpose ----
    __shared__ bf16_t tile[64][130];
#pragma unroll
    for (int j = 0; j < 32; ++j) {
        int linear = tid + 256 * j;
        int sl = linear >> 7, dh = linear & 127;
        tile[sl][dh] = qkv[(size_t)(sb + sl) * 4608 + 2 * D_MODEL + h * DHD + dh];
    }
    __syncthreads();
#pragma unroll
    for (int j = 0; j < 32; ++j) {
        int linear = tid + 256 * j;
        int dh = linear >> 6, sl = linear & 63;
        vt[((size_t)h * DHD + dh) * S_TOT + sb + sl] = tile[sl][dh];
    }
}

// ---------------------------------------------------------------------------
// Flash attention, KV-split, 8 waves x QBLK=128 (gemmW mechanism: K/V staging,
// VALU, and barriers per q-row halved). grid (12,12,KVSPLIT), 512 threads.
// Single-buffer 48 KB LDS (K 16K + V 16K + P 16K) -> 3 blk/CU cap.
// ---------------------------------------------------------------------------
__global__ __launch_bounds__(512)
void attn_k(const bf16_t* __restrict__ qbuf, const bf16_t* __restrict__ kbuf,
            const bf16_t* __restrict__ vt,
            float* __restrict__ part_o, float* __restrict__ part_ml) {
    __shared__ bf16_t Ks[64 * 128];
    __shared__ bf16_t Vs[128 * 64];
    __shared__ bf16_t P[8][16 * 64];
    int h = blockIdx.x, qblk = blockIdx.y, z = blockIdx.z;
    int q0 = qblk * 128;
    int tid = threadIdx.x, wid = tid >> 6, lane = tid & 63;
    int lr = lane & 15, lg = lane >> 4;

    const bf16_t* Qp = qbuf + ((size_t)h * S_TOT + q0 + wid * 16 + lr) * DHD;
    bf16x8 qf[4];
#pragma unroll
    for (int kk = 0; kk < 4; ++kk) qf[kk] = *(const bf16x8*)(Qp + (kk * 4 + lg) * 8);

    // K staging: 2 issues x 32 rows; wave covers 4 rows/issue.
    const int sKr = wid * 4 + (lane >> 4);           // 0..31
    const int cK = lane & 15;
    const bf16_t* Kb = kbuf + ((size_t)h * S_TOT + sKr) * DHD + ((cK ^ (sKr & 7)) * 8);
    // V staging: 2 issues x 64 rows; wave covers 8 rows/issue.
    const int sVr = wid * 8 + (lane >> 3);           // 0..63
    const int cV = lane & 7;
    const bf16_t* Vb = vt + ((size_t)h * DHD + sVr) * S_TOT + ((cV ^ (sVr & 7)) * 8);

    f32x4 of[8] = {};
    float m[4] = {-1e30f, -1e30f, -1e30f, -1e30f};
    float l[4] = {};
    const int kv0 = z * (S_TOT / KVSPLIT);
    const int nt = (S_TOT / KVSPLIT) / 64;

    for (int t = 0; t < nt; ++t) {
        const int kb0 = kv0 + t * 64;
#pragma unroll
        for (int j = 0; j < 2; ++j) {
            gload16(Kb + (size_t)(kb0 + j * 32) * DHD, &Ks[(wid * 4) * 128 + j * 4096]);
            gload16(Vb + kb0 + (size_t)j * 64 * S_TOT, &Vs[(wid * 8) * 64 + j * 4096]);
        }
        asm volatile("s_waitcnt vmcnt(0)" ::: "memory");
        __builtin_amdgcn_s_barrier();          // K/V tile ready
        f32x4 sf[4] = {};
        __builtin_amdgcn_s_setprio(1);
#pragma unroll
        for (int n = 0; n < 4; ++n) {
#pragma unroll
            for (int kk = 0; kk < 4; ++kk) {
                bf16x8 kf = *(const bf16x8*)&Ks[(n * 16 + lr) * 128 + (((kk * 4 + lg) ^ (lr & 7)) * 8)];
                sf[n] = __builtin_amdgcn_mfma_f32_16x16x32_bf16(qf[kk], kf, sf[n], 0, 0, 0);
            }
        }
        __builtin_amdgcn_s_setprio(0);
        float bm[4], alpha[4], rs[4];
#pragma unroll
        for (int r = 0; r < 4; ++r)
            bm[r] = fmaxf(fmaxf(sf[0][r], sf[1][r]), fmaxf(sf[2][r], sf[3][r]));
#pragma unroll
        for (int mask = 1; mask < 16; mask <<= 1)
#pragma unroll
            for (int r = 0; r < 4; ++r) bm[r] = fmaxf(bm[r], __shfl_xor(bm[r], mask));
#pragma unroll
        for (int r = 0; r < 4; ++r) {
            float mn = fmaxf(m[r], bm[r]);
            alpha[r] = __expf(m[r] - mn);
            m[r] = mn;
            rs[r] = 0.f;
        }
#pragma unroll
        for (int n = 0; n < 4; ++n)
#pragma unroll
            for (int r = 0; r < 4; ++r) {
                float p = __expf(sf[n][r] - m[r]);
                rs[r] += p;
                int row = lg * 4 + r, col = n * 16 + lr;
                P[wid][row * 64 + ((((col >> 3) ^ (row & 7)) << 3) | (col & 7))] = (bf16_t)p;
            }
#pragma unroll
        for (int mask = 1; mask < 16; mask <<= 1)
#pragma unroll
            for (int r = 0; r < 4; ++r) rs[r] += __shfl_xor(rs[r], mask);
#pragma unroll
        for (int r = 0; r < 4; ++r) l[r] = l[r] * alpha[r] + rs[r];
#pragma unroll
        for (int nf = 0; nf < 8; ++nf)
#pragma unroll
            for (int r = 0; r < 4; ++r) of[nf][r] *= alpha[r];
        __builtin_amdgcn_s_setprio(1);
#pragma unroll
        for (int kk2 = 0; kk2 < 2; ++kk2) {
            bf16x8 pf = *(const bf16x8*)&P[wid][lr * 64 + (((kk2 * 4 + lg) ^ (lr & 7)) * 8)];
#pragma unroll
            for (int nf = 0; nf < 8; ++nf) {
                bf16x8 vf = *(const bf16x8*)&Vs[(nf * 16 + lr) * 64 + (((kk2 * 4 + lg) ^ (lr & 7)) * 8)];
                of[nf] = __builtin_amdgcn_mfma_f32_16x16x32_bf16(pf, vf, of[nf], 0, 0, 0);
            }
        }
        __builtin_amdgcn_s_setprio(0);
        __builtin_amdgcn_s_barrier();          // all waves done reading K/V
    }
    int hq = h * 12 + qblk;                    // 128-row partial index
    float* po = part_o + ((size_t)z * 144 + hq) * 16384;
    int rb = wid * 16 + lg * 4;
#pragma unroll
    for (int r = 0; r < 4; ++r)
#pragma unroll
        for (int nf = 0; nf < 8; ++nf)
            po[(rb + r) * 128 + nf * 16 + lr] = of[nf][r];
    if (lr == 0) {
#pragma unroll
        for (int r = 0; r < 4; ++r) {
            size_t mi = (((size_t)z * 144 + hq) * 128 + rb + r) * 2;
            part_ml[mi]     = m[r];
            part_ml[mi + 1] = l[r];
        }
    }
}

// ---------------------------------------------------------------------------
// KV-split reduce: combine KVSPLIT partials -> bf16 o (S, D). grid 288 x 256.
// Partials stored per 128-row block (hq = h*12 + q/128).
// ---------------------------------------------------------------------------
__global__ __launch_bounds__(256)
void attn_red(const float* __restrict__ part_o, const float* __restrict__ part_ml,
              bf16_t* __restrict__ o) {
    int b = blockIdx.x;
    int h = b / 24, qi = b % 24;
    int hq = h * 12 + (qi >> 1), roff = (qi & 1) * 64;
    int q0 = qi * 64;
    __shared__ float wz[KVSPLIT][64];
    __shared__ float invL[64];
    int tid = threadIdx.x;
    if (tid < 64) {
        float mz[KVSPLIT], lz[KVSPLIT];
#pragma unroll
        for (int zz = 0; zz < KVSPLIT; ++zz) {
            size_t mi = (((size_t)zz * 144 + hq) * 128 + roff + tid) * 2;
            mz[zz] = part_ml[mi];
            lz[zz] = part_ml[mi + 1];
        }
        float M = mz[0];
#pragma unroll
        for (int zz = 1; zz < KVSPLIT; ++zz) M = fmaxf(M, mz[zz]);
        float L = 0.f;
#pragma unroll
        for (int zz = 0; zz < KVSPLIT; ++zz) {
            float w = __expf(mz[zz] - M);
            wz[zz][tid] = w;
            L += w * lz[zz];
        }
        invL[tid] = 1.0f / L;
    }
    __syncthreads();
#pragma unroll
    for (int i = 0; i < 8; ++i) {
        int e4 = tid + 256 * i;
        int row = e4 >> 5, c4 = e4 & 31;
        f32x4 acc = {};
#pragma unroll
        for (int zz = 0; zz < KVSPLIT; ++zz) {
            f32x4 v = *(const f32x4*)&part_o[((size_t)zz * 144 + hq) * 16384 + (roff + row) * 128 + c4 * 4];
            float w = wz[zz][row];
            acc[0] += v[0] * w; acc[1] += v[1] * w; acc[2] += v[2] * w; acc[3] += v[3] * w;
        }
        float il = invL[row];
        bf16x4 r;
        r[0] = (bf16_t)(acc[0] * il); r[1] = (bf16_t)(acc[1] * il);
        r[2] = (bf16_t)(acc[2] * il); r[3] = (bf16_t)(acc[3] * il);
        *(bf16x4*)&o[(size_t)(q0 + row) * D_MODEL + h * DHD + c4 * 4] = r;
    }
}

// ---------------------------------------------------------------------------
extern "C" void kernel_launch(void* const* d_in, const int* in_sizes, int n_in,
                              void* d_out, int out_size, void* d_ws, size_t ws_size,
                              hipStream_t stream) {
    const float* hidden  = (const float*)d_in[0];
    const float* encoder = (const float*)d_in[1];
    const float* temb    = (const float*)d_in[2];
    const float* rope    = (const float*)d_in[3];
    const float* adaln_img_w = (const float*)d_in[4];
    const float* adaln_img_b = (const float*)d_in[5];
    const float* adaln_txt_w = (const float*)d_in[6];
    const float* adaln_txt_b = (const float*)d_in[7];
    const float* qkv_img_w = (const float*)d_in[8];
    const float* qkv_img_b = (const float*)d_in[9];
    const float* qkv_txt_w = (const float*)d_in[10];
    const float* qkv_txt_b = (const float*)d_in[11];
    const float* qn_img = (const float*)d_in[12];
    const float* kn_img = (const float*)d_in[13];
    const float* qn_txt = (const float*)d_in[14];
    const float* kn_txt = (const float*)d_in[15];
    const float* out_img_w = (const float*)d_in[16];
    const float* out_img_b = (const float*)d_in[17];
    const float* out_txt_w = (const float*)d_in[18];
    const float* out_txt_b = (const float*)d_in[19];
    const float* mlp_img_w1 = (const float*)d_in[20];
    const float* mlp_img_b1 = (const float*)d_in[21];
    const float* mlp_img_w2 = (const float*)d_in[22];
    const float* mlp_img_b2 = (const float*)d_in[23];
    const float* mlp_txt_w1 = (const float*)d_in[24];
    const float* mlp_txt_b1 = (const float*)d_in[25];
    const float* mlp_txt_w2 = (const float*)d_in[26];
    const float* mlp_txt_b2 = (const float*)d_in[27];
    float* dout = (float*)d_out;
    char* wsb = (char*)d_ws;

    // ws layout (byte offsets), total 70,852,608 B = 67.6 MB.
    float*  emb_i = (float*)(wsb);                    // 9216 f32
    float*  emb_t = (float*)(wsb + 36864);            // 9216 f32
    bf16_t* wreg  = (bf16_t*)(wsb + 73728);           // 37.75 MB (weights, reused per stage)
    float*  part  = (float*)(wsb + 73728);            // adaln partials overlay
    float*  part_o = (float*)(wsb + 73728);           // attn partial O overlay (37.7 MB)
    bf16_t* n1    = (bf16_t*)(wsb + 37822464);        // 1536x1536 bf16 (LN1, later LN2)
    float*  part_ml = (float*)(wsb + 37822464);       // attn (m,l) overlay (n1 dead there)
    bf16_t* qkvb  = (bf16_t*)(wsb + 42541056);        // 1536x4608 bf16
    bf16_t* obuf  = qkvb;                             // alias (qkvb dead after qkv_post)
    bf16_t* ffb   = qkvb + 2359296;                   // 1536x6144 bf16 (bytes 47259648..66134016)
    bf16_t* qb    = (bf16_t*)(wsb + 56696832);        // 12x1536x128 bf16
    bf16_t* kb    = (bf16_t*)(wsb + 61415424);
    bf16_t* vt    = (bf16_t*)(wsb + 66134016);
    // K-split partial overlays (bf16 [z][1536][1536], 4,718,592 B each).
    // INVARIANT: MLP2 partial slots must NOT overlap ffb (47259648..66134016).
    bf16_t* pout = (bf16_t*)(wsb + 47259648);  // out-proj z=0,1 (ffb head; dead until MLP1)
    bf16_t* pm2  = (bf16_t*)(wsb + 37822464);  // MLP2 z=0,1 (n1+obuf; ends at ffb start)
    bf16_t* pm2b = (bf16_t*)(wsb + 66134016);  // MLP2 z=2 (vt; starts at ffb end)

    // 1. adaLN (K-split + reduce)
    adaln_p<<<dim3(72, 8), 256, 0, stream>>>(temb, adaln_img_w, adaln_txt_w, part);
    adaln_r<<<72, 256, 0, stream>>>(part, adaln_img_b, adaln_txt_b, emb_i, emb_t);
    // 2. LN1 + modulate -> bf16
    ln_mod<<<S_TOT, 256, 0, stream>>>(encoder, hidden, emb_t, emb_i, 0, 1, n1);
    // 3. QKV (432 blocks, gemmW 8-wave)
    conv_wt<1536, 4608><<<dim3(72, 24, 2), 256, 0, stream>>>(qkv_txt_w, qkv_img_w, wreg);
    gemmW<0><<<dim3(36, 12), 512, 0, stream>>>(
        n1, D_MODEL, wreg, 1536, 4608 * 1536, qkv_txt_b, qkv_img_b,
        qkvb, nullptr, 4608, 1536);
    // 4. fused RMS+RoPE (q,k) + V transpose
    qkv_post<<<dim3(12, 24), 256, 0, stream>>>(qkvb, rope, qn_img, kn_img, qn_txt, kn_txt,
                                               qb, kb, vt);
    // 5. attention (KV-split, 8-wave QBLK=128) + reduce -> o bf16
    attn_k<<<dim3(12, 12, KVSPLIT), 512, 0, stream>>>(qb, kb, vt, part_o, part_ml);
    attn_red<<<288, 256, 0, stream>>>(part_o, part_ml, obuf);
    // 6. out-proj: K-split x2 (288 blocks, gemmW) + fused reduce+LN2 epilogue
    conv_wt<1536, 1536><<<dim3(24, 24, 2), 256, 0, stream>>>(out_txt_w, out_img_w, wreg);
    gemmW<3><<<dim3(12, 12, 2), 512, 0, stream>>>(
        obuf, D_MODEL, wreg, 1536, 1536 * 1536, nullptr, nullptr,
        pout, nullptr, D_MODEL, 768);
    red_ln<<<S_TOT, 256, 0, stream>>>(
        pout, out_txt_b, out_img_b,
        emb_t + 2 * D_MODEL, emb_i + 2 * D_MODEL, encoder, hidden,
        emb_t, emb_i, dout, n1);
    // 7. MLP up + gelu -> bf16 ff (576 blocks, gemmW)
    conv_wt<1536, 6144><<<dim3(96, 24, 2), 256, 0, stream>>>(mlp_txt_w1, mlp_img_w1, wreg);
    gemmW<1><<<dim3(48, 12), 512, 0, stream>>>(
        n1, D_MODEL, wreg, 1536, 6144 * 1536, mlp_txt_b1, mlp_img_b1,
        ffb, nullptr, FF_DIM, 1536);
    // 8. MLP down: K-split x3 (432 blocks, gemmW) + fused reduce (in-place)
    conv_wt<6144, 1536><<<dim3(24, 96, 2), 256, 0, stream>>>(mlp_txt_w2, mlp_img_w2, wreg);
    gemmW<3><<<dim3(12, 12, 3), 512, 0, stream>>>(
        ffb, FF_DIM, wreg, 6144, 1536 * 6144, nullptr, nullptr,
        pm2, pm2b, D_MODEL, 2048);
    gemm_red<3><<<S_TOT, 256, 0, stream>>>(
        pm2, pm2b, mlp_txt_b2, mlp_img_b2,
        emb_t + 5 * D_MODEL, emb_i + 5 * D_MODEL,
        dout, dout + (size_t)S_TXT * D_MODEL, dout);
    (void)in_sizes; (void)n_in; (void)out_size; (void)ws_size;
}